// Round 11
// baseline (323.498 us; speedup 1.0000x reference)
//
#include <hip/hip_runtime.h>
#include <math.h>

#define B_ 2
#define S_ 1024
#define D_ 512
#define N_ 4096
#define H_ 8
#define DH_ 64
#define NCAND 288   // 9 neighbor cells * 32 entries
#define TOPK 32
#define NTOK (B_*S_)   // 2048
#define NG2 1152       // max 2-token same-cell groups (8*144)

#define NROWS 16384       // B*H*S
#define NSLOT_BH 4608     // sum over rows i<1024 of (i/128+1)
#define NSLOTS (16*NSLOT_BH)

typedef __attribute__((ext_vector_type(8))) short short8;
typedef __attribute__((ext_vector_type(4))) float f32x4;

__device__ __forceinline__ float wave_sum(float v) {
    #pragma unroll
    for (int o = 32; o; o >>= 1) v += __shfl_xor(v, o);
    return v;
}
__device__ __forceinline__ float wave_max(float v) {
    #pragma unroll
    for (int o = 32; o; o >>= 1) v = fmaxf(v, __shfl_xor(v, o));
    return v;
}
__device__ __forceinline__ ushort f2b_rn(float f) {
    unsigned u = __float_as_uint(f);
    return (ushort)((u + 0x7FFFu + ((u >> 16) & 1u)) >> 16);
}
__device__ __forceinline__ float b2f(ushort h) {
    return __uint_as_float(((unsigned)h) << 16);
}
__device__ __forceinline__ int swzi(int row, int c8) {
    return row * 64 + ((c8 ^ (row & 7)) << 3);
}

// ---------- sort (blocks 0-1) + wprep (2-65) + neuron bf16 split (66-321) --
__global__ __launch_bounds__(1024) void sort_wprep_kernel(
    const float* __restrict__ qk_pos, const float* __restrict__ v_pos,
    const float* __restrict__ pos_min, const float* __restrict__ pos_range,
    int* __restrict__ order_qk, int* __restrict__ order_v,
    int2* __restrict__ desc_qk, int2* __restrict__ desc_v,
    float* __restrict__ posacc,
    const float* __restrict__ W, ushort* __restrict__ Wth, ushort* __restrict__ Wtl,
    const float* __restrict__ qk_neurons, const float* __restrict__ v_neurons,
    ushort* __restrict__ nqh, ushort* __restrict__ nql,
    ushort* __restrict__ nvh, ushort* __restrict__ nvl)
{
    __shared__ int hist[256], tmp[256], offs[256], startc[256], gcnt[256];
    __shared__ float tile[64][65];
    const int t = threadIdx.x;
    const int bid = blockIdx.x;

    if (bid >= 66) {
        // ---- neuron table bf16 hi/lo split (dot phase reads these) ----
        const int cid = bid - 66;                 // 0..255
        const float* src = (cid & 1) ? v_neurons : qk_neurons;
        ushort* dh = (cid & 1) ? nvh : nqh;
        ushort* dl = (cid & 1) ? nvl : nql;
        const size_t base = (size_t)(cid >> 1) * 16384 + (size_t)t * 16;
        union { float4 f4[4]; float f[16]; } xf;
        xf.f4[0] = *(const float4*)(src + base);
        xf.f4[1] = *(const float4*)(src + base + 4);
        xf.f4[2] = *(const float4*)(src + base + 8);
        xf.f4[3] = *(const float4*)(src + base + 12);
        union { uint4 q[2]; ushort u[16]; } Hh, Ll;
        #pragma unroll
        for (int i = 0; i < 16; i++) {
            Hh.u[i] = f2b_rn(xf.f[i]);
            Ll.u[i] = f2b_rn(xf.f[i] - b2f(Hh.u[i]));
        }
        *(uint4*)(dh + base)     = Hh.q[0];
        *(uint4*)(dh + base + 8) = Hh.q[1];
        *(uint4*)(dl + base)     = Ll.q[0];
        *(uint4*)(dl + base + 8) = Ll.q[1];
        return;
    }

    if (bid >= 2) {
        // ---- wprep: transpose + bf16 hi/lo split of expand_O ----
        const int bb = bid - 2;
        const int bx = bb & 7, by = bb >> 3;   // 8x8 tiles of 64x64
        if (t < 256) {
            const int r = t >> 4, c4 = (t & 15) * 4;
            #pragma unroll
            for (int rr = 0; rr < 64; rr += 16) {
                const float4 v = *(const float4*)(W + (size_t)(by * 64 + rr + r) * 512 + bx * 64 + c4);
                *(float4*)&tile[rr + r][c4] = v;            // tile[k][c]
            }
        }
        __syncthreads();
        if (t < 256) {
            const int r = t >> 4, c4 = (t & 15) * 4;
            #pragma unroll
            for (int cc = 0; cc < 64; cc += 16) {
                const int c = cc + r;
                ushort h[4], l[4];
                #pragma unroll
                for (int i = 0; i < 4; i++) {
                    float f = tile[c4 + i][c];
                    h[i] = f2b_rn(f);
                    l[i] = f2b_rn(f - b2f(h[i]));
                }
                *(uint2*)&Wth[(size_t)(bx * 64 + c) * 512 + by * 64 + c4] = *(uint2*)h;
                *(uint2*)&Wtl[(size_t)(bx * 64 + c) * 512 + by * 64 + c4] = *(uint2*)l;
            }
        }
        return;
    }

    // ---- sort pass ----
    const int pass = bid;
    if (pass == 0 && t < 32) posacc[t] = 0.f;
    const float pm0 = pos_min[0], pm1 = pos_min[1];
    const float pr0 = pos_range[0], pr1 = pos_range[1];
    const float* pos = pass ? v_pos : qk_pos;
    int* order = pass ? order_v : order_qk;
    int2* desc = pass ? desc_v : desc_qk;
    if (t < NG2) desc[t] = make_int2(0, 0);
    if (t + 1024 < NG2) desc[t + 1024] = make_int2(0, 0);
    if (t < 256) hist[t] = 0;
    __syncthreads();
    int cell[2];
    #pragma unroll
    for (int k = 0; k < 2; k++) {
        int tok = t + k * 1024;
        float p0 = pos[tok * 2], p1 = pos[tok * 2 + 1];
        int cx = min(max((int)((p0 - pm0) / pr0 * 16.f), 0), 15);
        int cy = min(max((int)((p1 - pm1) / pr1 * 16.f), 0), 15);
        cell[k] = cx * 16 + cy;
        atomicAdd(&hist[cell[k]], 1);
    }
    __syncthreads();
    if (t < 256) tmp[t] = hist[t];
    __syncthreads();
    for (int d = 1; d < 256; d <<= 1) {
        int v = 0;
        if (t < 256 && t >= d) v = tmp[t - d];
        __syncthreads();
        if (t < 256) tmp[t] += v;
        __syncthreads();
    }
    if (t < 256) {
        startc[t] = tmp[t] - hist[t];
        offs[t]   = startc[t];
        gcnt[t]   = (hist[t] + 1) >> 1;
    }
    __syncthreads();
    #pragma unroll
    for (int k = 0; k < 2; k++) {
        int tok = t + k * 1024;
        int p = atomicAdd(&offs[cell[k]], 1);
        order[p] = tok;
    }
    __syncthreads();
    if (t < 256) tmp[t] = gcnt[t];
    __syncthreads();
    for (int d = 1; d < 256; d <<= 1) {
        int v = 0;
        if (t < 256 && t >= d) v = tmp[t - d];
        __syncthreads();
        if (t < 256) tmp[t] += v;
        __syncthreads();
    }
    if (t < 256) {
        int g0 = tmp[t] - gcnt[t];
        for (int k = 0; k < gcnt[t]; k++)
            desc[g0 + k] = make_int2(startc[t] + 2 * k, min(2, hist[t] - 2 * k));
    }
}

// ---------- fused QK+V kernel: MFMA dot phase (4-term bf16 split) ----------
// A = 2 token x-vectors (rows 2-15 zero), B = pre-split neuron rows.
// 4-term (hi*hi+hi*lo+lo*hi+lo*lo) keeps act error ~2^-18 rel -- same order
// as the fp32 reorder noise r1-r7 already injected (absmax bit-stable).
// Gather phase unchanged (fp32 neurons).
__global__ __launch_bounds__(256) void qkv_fused(
    const int2* __restrict__ desc_qk, const int* __restrict__ order_qk,
    const int2* __restrict__ desc_v,  const int* __restrict__ order_v,
    const float* __restrict__ x,
    const float* __restrict__ qk_pos, const float* __restrict__ v_pos,
    const float* __restrict__ tauQ, const float* __restrict__ tauK,
    const float* __restrict__ tauV,
    const float* __restrict__ qk_neurons, const float* __restrict__ v_neurons,
    const ushort* __restrict__ nqh, const ushort* __restrict__ nql,
    const ushort* __restrict__ nvh, const ushort* __restrict__ nvl,
    const float* __restrict__ npos_qk, const float* __restrict__ npos_v,
    const int* __restrict__ cm_qk, const int* __restrict__ cm_v,
    const float* __restrict__ pos_min, const float* __restrict__ pos_range,
    float* __restrict__ Q, float* __restrict__ K, float* __restrict__ V,
    float* __restrict__ posacc)
{
    const int bid = blockIdx.x;
    const int role = bid & 1;
    const int g = bid >> 1;
    const int gid = (g & 7) * 144 + (g >> 3);
    const int2 dsc = role ? desc_v[gid] : desc_qk[gid];
    const int gstart = dsc.x, count = dsc.y;
    if (count == 0) return;

    const int*   order   = role ? order_v   : order_qk;
    const float* pose    = role ? v_pos     : qk_pos;
    const float* neurons = role ? v_neurons : qk_neurons;
    const ushort* nh     = role ? nvh       : nqh;
    const ushort* nl     = role ? nvl       : nql;
    const float* npos    = role ? npos_v    : npos_qk;
    const int*   cmap    = role ? cm_v      : cm_qk;

    __shared__ int   idx[NCAND];
    __shared__ float msk[NCAND];
    __shared__ float act[2][NCAND];
    __shared__ int   ci[2][NCAND];
    __shared__ float cw1[2][NCAND], cw2[2][NCAND];
    __shared__ int   toks[2], cnt2[2];
    __shared__ float red[2][2][4];
    __shared__ float redc;
    __shared__ __align__(16) ushort xh[2][512], xl[2][512];

    const int t = threadIdx.x, wid = t >> 6, lane = t & 63;
    if (t < 2) { toks[t] = order[gstart + min(t, count - 1)]; cnt2[t] = 0; }
    __syncthreads();
    const int token0 = toks[0];

    const float pm0 = pos_min[0], pm1 = pos_min[1];
    const float pr0 = pos_range[0], pr1 = pos_range[1];
    {
        const float p0 = pose[token0 * 2], p1 = pose[token0 * 2 + 1];
        const int cx = min(max((int)((p0 - pm0) / pr0 * 16.f), 0), 15);
        const int cy = min(max((int)((p1 - pm1) / pr1 * 16.f), 0), 15);
        for (int c = t; c < NCAND; c += 256) {
            int o = c >> 5, ms = c & 31;
            int nx = min(max(cx + o / 3 - 1, 0), 15), ny = min(max(cy + o % 3 - 1, 0), 15);
            int cand = cmap[(nx * 16 + ny) * 32 + ms];
            idx[c] = cand >= 0 ? cand : 0;
            msk[c] = cand >= 0 ? 1.f : 0.f;
        }
    }
    // stage both tokens' x as bf16 hi/lo in LDS (A-operand source)
    for (int e = t; e < 1024; e += 256) {
        const int tok = e >> 9, k = e & 511;
        const float f = x[(size_t)toks[tok] * D_ + k];
        const ushort hh = f2b_rn(f);
        xh[tok][k] = hh;
        xl[tok][k] = f2b_rn(f - b2f(hh));
    }
    __syncthreads();

    // --- dot phase via MFMA: wave wid owns tiles [tbase, tbase+tcnt) ---
    {
        const int col = lane & 15, kg8 = (lane >> 4) << 3;
        const int tbase = wid * 4 + ((wid + 1) >> 1);   // 0,5,9,14
        const int tcnt = 5 - (wid & 1);                 // 5,4,5,4
        const f32x4 fz = {0.f, 0.f, 0.f, 0.f};
        f32x4 acc[5];
        int noff[5];
        #pragma unroll
        for (int T = 0; T < 5; T++) {
            acc[T] = fz;
            noff[T] = (T < tcnt) ? idx[(tbase + T) * 16 + col] * 512 + kg8 : 0;
        }
        const short8 z8 = {0, 0, 0, 0, 0, 0, 0, 0};
        for (int s = 0; s < 16; s++) {
            short8 ah = z8, al = z8;
            if (col < 2) {
                ah = *(const short8*)&xh[col][s * 32 + kg8];
                al = *(const short8*)&xl[col][s * 32 + kg8];
            }
            #pragma unroll
            for (int T = 0; T < 5; T++) {
                if (T < tcnt) {
                    const short8 bh = *(const short8*)(nh + noff[T] + s * 32);
                    const short8 bl = *(const short8*)(nl + noff[T] + s * 32);
                    acc[T] = __builtin_amdgcn_mfma_f32_16x16x32_bf16(ah, bh, acc[T], 0, 0, 0);
                    acc[T] = __builtin_amdgcn_mfma_f32_16x16x32_bf16(al, bh, acc[T], 0, 0, 0);
                    acc[T] = __builtin_amdgcn_mfma_f32_16x16x32_bf16(ah, bl, acc[T], 0, 0, 0);
                    acc[T] = __builtin_amdgcn_mfma_f32_16x16x32_bf16(al, bl, acc[T], 0, 0, 0);
                }
            }
        }
        // D: row = (lane>>4)*4 + reg = token (0,1), col = lane&15 = cand
        if (lane < 16) {
            #pragma unroll
            for (int T = 0; T < 5; T++) {
                if (T < tcnt) {
                    const int c = (tbase + T) * 16 + lane;
                    const float mv = msk[c];
                    act[0][c] = (mv != 0.f) ? acc[T][0] : -1e9f;
                    act[1][c] = (mv != 0.f) ? acc[T][1] : -1e9f;
                }
            }
        }
    }
    __syncthreads();

    const int tk = wid >> 1, sw = wid & 1, tt = t & 127;
    const int token = toks[tk];

    if (sw == 0) {
        unsigned ej[5];
        #pragma unroll
        for (int k = 0; k < 5; k++) {
            int j = lane + 64 * k;
            float f = (j < NCAND) ? act[tk][j] : -1e30f;
            unsigned uu = __float_as_uint(f);
            ej[k] = (uu & 0x80000000u) ? ~uu : (uu | 0x80000000u);
        }
        unsigned T = 0u;
        for (int bit = 31; bit >= 0; bit--) {
            const unsigned cand = T | (1u << bit);
            int c = 0;
            #pragma unroll
            for (int k = 0; k < 5; k++)
                c += __popcll(__ballot(ej[k] >= cand));
            if (c >= TOPK) T = cand;
        }
        int base = 0;
        const unsigned long long below = (lane == 0) ? 0ull
                                       : (~0ull >> (64 - lane));
        #pragma unroll
        for (int k = 0; k < 5; k++) {
            const unsigned long long mk2 = __ballot(ej[k] >= T);
            if (ej[k] >= T) {
                int pos = base + __popcll(mk2 & below);
                ci[tk][pos] = lane + 64 * k;
            }
            base += __popcll(mk2);
        }
        if (lane == 0) cnt2[tk] = base;
    }
    if (wid == 0) {
        float cmv = 0.f;
        for (int c = lane; c < NCAND; c += 64) cmv += msk[c];
        cmv = wave_sum(cmv);
        if (lane == 0) redc = cmv;
    }
    __syncthreads();
    const float cm = redc;
    const int n = cnt2[tk];

    if (role == 0) {
        const float tq = tauQ[token], tkk = tauK[token];
        float sQ = 0.f, sK = 0.f, mQ = 0.f, mK = 0.f;
        for (int p = tt; p < n; p += 128) {
            float s = act[tk][ci[tk][p]];
            float rq = s - tq;
            float gq = (rq > 0.f) ? rq : 1e-8f * __expf(rq);
            float egq = __expf(gq) - 1.f;
            float rk = s - tkk;
            float gk = (rk > 0.f) ? rk : 1e-8f * __expf(rk);
            float egk = __expf(gk) - 1.f;
            cw1[tk][p] = egq; cw2[tk][p] = egk;
            sQ += egq; sK += egk;
            mQ = fmaxf(mQ, egq); mK = fmaxf(mK, egk);
        }
        sQ = wave_sum(sQ); mQ = wave_max(mQ);
        sK = wave_sum(sK); mK = wave_max(mK);
        if (lane == 0) {
            red[tk][sw][0] = sQ; red[tk][sw][1] = mQ;
            red[tk][sw][2] = sK; red[tk][sw][3] = mK;
        }
        __syncthreads();
        const float scQ = tanhf(fmaxf(red[tk][0][1], red[tk][1][1]))
                        / (red[tk][0][0] + red[tk][1][0] + 1e-8f);
        const float scK = tanhf(fmaxf(red[tk][0][3], red[tk][1][3]))
                        / (red[tk][0][2] + red[tk][1][2] + 1e-8f);
        __syncthreads();

        const float qp0 = pose[token * 2], qp1 = pose[token * 2 + 1];
        float plq = 0.f;
        for (int p = tt; p < n; p += 128) {
            int e = ci[tk][p];
            int id = idx[e];
            float m = msk[e], a = act[tk][e];
            float gq = cw1[tk][p] * scQ;
            cw1[tk][p] = a * gq * m;
            cw2[tk][p] = a * cw2[tk][p] * scK * m;
            ci[tk][p] = id;
            float d0 = qp0 - npos[id * 2], d1 = qp1 - npos[id * 2 + 1];
            plq += gq * (d0 * d0 + d1 * d1) * m;
        }
        plq = wave_sum(plq);
        if (lane == 0) red[tk][sw][0] = plq;
        __syncthreads();
        if (tt == 0 && tk < count) {
            int chunk = (token & 1023) >> 7;
            atomicAdd(&posacc[chunk], red[tk][0][0] + red[tk][1][0]);
            atomicAdd(&posacc[8 + chunk], cm);
        }

        if (tk < count) {
            float4 qa = {0,0,0,0}, ka = {0,0,0,0};
            int p = 0;
            for (; p + 1 < n; p += 2) {
                const float4 rA = *(const float4*)(neurons + (size_t)ci[tk][p] * D_ + tt * 4);
                const float4 rB = *(const float4*)(neurons + (size_t)ci[tk][p + 1] * D_ + tt * 4);
                const float wA = cw1[tk][p], bA = cw2[tk][p];
                const float wB = cw1[tk][p + 1], bB = cw2[tk][p + 1];
                qa.x += wA * rA.x + wB * rB.x; qa.y += wA * rA.y + wB * rB.y;
                qa.z += wA * rA.z + wB * rB.z; qa.w += wA * rA.w + wB * rB.w;
                ka.x += bA * rA.x + bB * rB.x; ka.y += bA * rA.y + bB * rB.y;
                ka.z += bA * rA.z + bB * rB.z; ka.w += bA * rA.w + bB * rB.w;
            }
            if (p < n) {
                const float4 rA = *(const float4*)(neurons + (size_t)ci[tk][p] * D_ + tt * 4);
                const float wA = cw1[tk][p], bA = cw2[tk][p];
                qa.x += wA * rA.x; qa.y += wA * rA.y; qa.z += wA * rA.z; qa.w += wA * rA.w;
                ka.x += bA * rA.x; ka.y += bA * rA.y; ka.z += bA * rA.z; ka.w += bA * rA.w;
            }
            *(float4*)(Q + (size_t)token * D_ + tt * 4) = qa;
            *(float4*)(K + (size_t)token * D_ + tt * 4) = ka;
        }
    } else {
        const float tv = tauV[token];
        float sV = 0.f, mV = 0.f;
        for (int p = tt; p < n; p += 128) {
            float s = act[tk][ci[tk][p]];
            float rv = s - tv;
            float gv = (rv > 0.f) ? rv : 1e-8f * __expf(rv);
            float egv = __expf(gv) - 1.f;
            cw1[tk][p] = egv;
            sV += egv; mV = fmaxf(mV, egv);
        }
        sV = wave_sum(sV); mV = wave_max(mV);
        if (lane == 0) { red[tk][sw][0] = sV; red[tk][sw][1] = mV; }
        __syncthreads();
        const float scV = tanhf(fmaxf(red[tk][0][1], red[tk][1][1]))
                        / (red[tk][0][0] + red[tk][1][0] + 1e-8f);
        __syncthreads();

        const float vp0 = pose[token * 2], vp1 = pose[token * 2 + 1];
        float plv = 0.f;
        for (int p = tt; p < n; p += 128) {
            int e = ci[tk][p];
            int id = idx[e];
            float m = msk[e], a = act[tk][e];
            float gv = cw1[tk][p] * scV;
            cw1[tk][p] = a * gv * m;
            ci[tk][p] = id;
            float d0 = vp0 - npos[id * 2], d1 = vp1 - npos[id * 2 + 1];
            plv += gv * (d0 * d0 + d1 * d1) * m;
        }
        plv = wave_sum(plv);
        if (lane == 0) red[tk][sw][0] = plv;
        __syncthreads();
        if (tt == 0 && tk < count) {
            int chunk = (token & 1023) >> 7;
            atomicAdd(&posacc[16 + chunk], red[tk][0][0] + red[tk][1][0]);
            atomicAdd(&posacc[24 + chunk], cm);
        }

        if (tk < count) {
            float4 va = {0,0,0,0};
            int p = 0;
            for (; p + 1 < n; p += 2) {
                const float4 rA = *(const float4*)(neurons + (size_t)ci[tk][p] * D_ + tt * 4);
                const float4 rB = *(const float4*)(neurons + (size_t)ci[tk][p + 1] * D_ + tt * 4);
                const float wA = cw1[tk][p], wB = cw1[tk][p + 1];
                va.x += wA * rA.x + wB * rB.x; va.y += wA * rA.y + wB * rB.y;
                va.z += wA * rA.z + wB * rB.z; va.w += wA * rA.w + wB * rB.w;
            }
            if (p < n) {
                const float4 rA = *(const float4*)(neurons + (size_t)ci[tk][p] * D_ + tt * 4);
                const float wA = cw1[tk][p];
                va.x += wA * rA.x; va.y += wA * rA.y; va.z += wA * rA.z; va.w += wA * rA.w;
            }
            *(float4*)(V + (size_t)token * D_ + tt * 4) = va;
        }
    }
}

// ---------- MFMA attention partials: KV tile = 128 keys, in-block merge ----
__global__ __launch_bounds__(256, 2) void attn_partial_kernel(
    const float* __restrict__ Q, const float* __restrict__ K,
    const float* __restrict__ V,
    float* __restrict__ pm, float* __restrict__ pl, float* __restrict__ po)
{
    const int bh = blockIdx.x & 15;
    int kq = blockIdx.x >> 4;            // 0..35
    int rblk = 0;
    while (kq >= rblk + 1) { kq -= rblk + 1; rblk++; }
    const int sp = kq;                   // 0..rblk
    const int b = bh >> 3, h = bh & 7;
    const int j0 = sp * 128;
    const int rbase = rblk * 128;

    __shared__ __align__(16) ushort sKhi[64 * 64], sKlo[64 * 64];
    __shared__ __align__(16) ushort sVthi[64 * 64], sVtlo[64 * 64];
    __shared__ __align__(16) float sPool[8192];   // Vf fp32 [64][65] then P bounce

    const int t = threadIdx.x;
    const int w = t >> 6, lane = t & 63;
    const int g = lane >> 4, ln = lane & 15;
    const int wrow = rbase + w * 32;

    // ---- Q fragments in registers (bf16 hi/lo), loaded once ----
    short8 qhi[2][2], qlo[2][2];
    #pragma unroll
    for (int qt = 0; qt < 2; qt++) {
        const int qrow = wrow + qt * 16 + ln;
        const float* Qg = Q + ((size_t)(b * S_ + qrow)) * D_ + h * DH_ + g * 8;
        #pragma unroll
        for (int ds = 0; ds < 2; ds++) {
            union { float4 f4[2]; float f[8]; } qf;
            qf.f4[0] = *(const float4*)(Qg + ds * 32);
            qf.f4[1] = *(const float4*)(Qg + ds * 32 + 4);
            union { short8 v; ushort u[8]; } uh, ul;
            #pragma unroll
            for (int i = 0; i < 8; i++) {
                uh.u[i] = f2b_rn(qf.f[i]);
                ul.u[i] = f2b_rn(qf.f[i] - b2f(uh.u[i]));
            }
            qhi[qt][ds] = uh.v; qlo[qt][ds] = ul.v;
        }
    }

    const f32x4 fzero = {0.f, 0.f, 0.f, 0.f};
    f32x4 ot[4][2];
    #pragma unroll
    for (int dt = 0; dt < 4; dt++)
        #pragma unroll
        for (int qt = 0; qt < 2; qt++)
            ot[dt][qt] = fzero;
    float m_run[2] = {-1e30f, -1e30f};
    float l_run[2] = {0.f, 0.f};

    for (int half = 0; half < 2; half++) {
        const int j0h = j0 + half * 64;
        __syncthreads();   // protect LDS before restage

        {
            const int srow = t >> 2, scol = (t & 3) << 4;
            const float* Kg = K + ((size_t)(b * S_ + j0h + srow)) * D_ + h * DH_ + scol;
            const float* Vg = V + ((size_t)(b * S_ + j0h + srow)) * D_ + h * DH_ + scol;
            union { float4 f4[4]; float f[16]; } kf, vf;
            kf.f4[0] = *(const float4*)(Kg);
            kf.f4[1] = *(const float4*)(Kg + 4);
            kf.f4[2] = *(const float4*)(Kg + 8);
            kf.f4[3] = *(const float4*)(Kg + 12);
            vf.f4[0] = *(const float4*)(Vg);
            vf.f4[1] = *(const float4*)(Vg + 4);
            vf.f4[2] = *(const float4*)(Vg + 8);
            vf.f4[3] = *(const float4*)(Vg + 12);
            union { uint4 d[2]; ushort u[16]; } uh, ul;
            #pragma unroll
            for (int i = 0; i < 16; i++) {
                uh.u[i] = f2b_rn(kf.f[i]);
                ul.u[i] = f2b_rn(kf.f[i] - b2f(uh.u[i]));
            }
            const int c8 = (t & 3) << 1;
            *(uint4*)&sKhi[swzi(srow, c8)]     = uh.d[0];
            *(uint4*)&sKhi[swzi(srow, c8 + 1)] = uh.d[1];
            *(uint4*)&sKlo[swzi(srow, c8)]     = ul.d[0];
            *(uint4*)&sKlo[swzi(srow, c8 + 1)] = ul.d[1];
            #pragma unroll
            for (int i = 0; i < 16; i++) sPool[srow * 65 + scol + i] = vf.f[i];
        }
        __syncthreads();
        {
            const int drow = t >> 2, kcol = (t & 3) << 4;
            union { uint4 d[2]; ushort u[16]; } uh, ul;
            #pragma unroll
            for (int i = 0; i < 16; i++) {
                const float f = sPool[(kcol + i) * 65 + drow];
                uh.u[i] = f2b_rn(f);
                ul.u[i] = f2b_rn(f - b2f(uh.u[i]));
            }
            const int c8 = (t & 3) << 1;
            *(uint4*)&sVthi[swzi(drow, c8)]     = uh.d[0];
            *(uint4*)&sVthi[swzi(drow, c8 + 1)] = uh.d[1];
            *(uint4*)&sVtlo[swzi(drow, c8)]     = ul.d[0];
            *(uint4*)&sVtlo[swzi(drow, c8 + 1)] = ul.d[1];
        }
        __syncthreads();

        if (wrow + 31 < j0h) continue;

        ushort* sPw = (ushort*)sPool + w * 4096;

        f32x4 sT[2][4];
        #pragma unroll
        for (int qt = 0; qt < 2; qt++)
            #pragma unroll
            for (int kt = 0; kt < 4; kt++)
                sT[qt][kt] = fzero;
        #pragma unroll
        for (int ds = 0; ds < 2; ds++) {
            #pragma unroll
            for (int kt = 0; kt < 4; kt++) {
                const int krow = kt * 16 + ln;
                const short8 khi = *(const short8*)&sKhi[swzi(krow, ds * 4 + g)];
                const short8 klo = *(const short8*)&sKlo[swzi(krow, ds * 4 + g)];
                #pragma unroll
                for (int qt = 0; qt < 2; qt++) {
                    sT[qt][kt] = __builtin_amdgcn_mfma_f32_16x16x32_bf16(khi, qhi[qt][ds], sT[qt][kt], 0, 0, 0);
                    sT[qt][kt] = __builtin_amdgcn_mfma_f32_16x16x32_bf16(khi, qlo[qt][ds], sT[qt][kt], 0, 0, 0);
                    sT[qt][kt] = __builtin_amdgcn_mfma_f32_16x16x32_bf16(klo, qhi[qt][ds], sT[qt][kt], 0, 0, 0);
                }
            }
        }

        #pragma unroll
        for (int qt = 0; qt < 2; qt++) {
            const int qg = wrow + qt * 16 + ln;
            float pv[16];
            float mq = -1e30f;
            #pragma unroll
            for (int kt = 0; kt < 4; kt++)
                #pragma unroll
                for (int r = 0; r < 4; r++) {
                    const int kg = j0h + kt * 16 + g * 4 + r;
                    float s = sT[qt][kt][r] * 0.125f;
                    s = (kg <= qg) ? s : -1e30f;
                    pv[kt * 4 + r] = s;
                    mq = fmaxf(mq, s);
                }
            mq = fmaxf(mq, __shfl_xor(mq, 16));
            mq = fmaxf(mq, __shfl_xor(mq, 32));
            const float mN = fmaxf(m_run[qt], mq);
            const float base = (mN < -1e29f) ? 0.f : mN;
            const float a = __expf(m_run[qt] - mN);
            m_run[qt] = mN;
            float lq = 0.f;
            #pragma unroll
            for (int i = 0; i < 16; i++) {
                const float e = __expf(pv[i] - base);
                pv[i] = e;
                lq += e;
            }
            lq += __shfl_xor(lq, 16);
            lq += __shfl_xor(lq, 32);
            l_run[qt] = l_run[qt] * a + lq;
            #pragma unroll
            for (int dt = 0; dt < 4; dt++)
                ot[dt][qt] *= a;

            const int qrow = qt * 16 + ln;
            #pragma unroll
            for (int kt = 0; kt < 4; kt++) {
                union { uint2 d; ushort u[4]; } h4, l4;
                #pragma unroll
                for (int r = 0; r < 4; r++) {
                    const float f = pv[kt * 4 + r];
                    h4.u[r] = f2b_rn(f);
                    l4.u[r] = f2b_rn(f - b2f(h4.u[r]));
                }
                const int c8 = kt * 2 + (g >> 1);
                const int idx = qrow * 64 + ((c8 ^ (qrow & 7)) << 3) + ((g & 1) << 2);
                *(uint2*)&sPw[idx] = h4.d;
                *(uint2*)&sPw[2048 + idx] = l4.d;
            }
        }

        #pragma unroll
        for (int ks = 0; ks < 2; ks++) {
            short8 pfh[2], pfl[2];
            #pragma unroll
            for (int qt = 0; qt < 2; qt++) {
                const int qrow = qt * 16 + ln;
                const int idx = qrow * 64 + (((ks * 4 + g) ^ (qrow & 7)) << 3);
                pfh[qt] = *(const short8*)&sPw[idx];
                pfl[qt] = *(const short8*)&sPw[2048 + idx];
            }
            #pragma unroll
            for (int dt = 0; dt < 4; dt++) {
                const int drow = dt * 16 + ln;
                const short8 vh = *(const short8*)&sVthi[swzi(drow, ks * 4 + g)];
                const short8 vl = *(const short8*)&sVtlo[swzi(drow, ks * 4 + g)];
                #pragma unroll
                for (int qt = 0; qt < 2; qt++) {
                    ot[dt][qt] = __builtin_amdgcn_mfma_f32_16x16x32_bf16(vh, pfh[qt], ot[dt][qt], 0, 0, 0);
                    ot[dt][qt] = __builtin_amdgcn_mfma_f32_16x16x32_bf16(vh, pfl[qt], ot[dt][qt], 0, 0, 0);
                    ot[dt][qt] = __builtin_amdgcn_mfma_f32_16x16x32_bf16(vl, pfh[qt], ot[dt][qt], 0, 0, 0);
                }
            }
        }
    }

    #pragma unroll
    for (int qt = 0; qt < 2; qt++) {
        const int qg = wrow + qt * 16 + ln;
        const int g2 = qg >> 7;                     // == rblk
        const size_t slot = (size_t)bh * NSLOT_BH + 64 * g2 * (g2 + 1)
                          + (size_t)(qg & 127) * (g2 + 1) + sp;
        if (g == 0) { pm[slot] = m_run[qt]; pl[slot] = l_run[qt]; }
        float* od = po + slot * 64 + g * 4;
        #pragma unroll
        for (int dt = 0; dt < 4; dt++)
            *(f32x4*)(od + dt * 16) = ot[dt][qt];
    }
}

// ---------- merge split partials (single-pass online merge) ----------
__global__ __launch_bounds__(256) void attn_combine_kernel(
    const float* __restrict__ pm, const float* __restrict__ pl,
    const float* __restrict__ po, float* __restrict__ AO)
{
    const int gth = blockIdx.x * 256 + threadIdx.x;
    const int r = gth >> 6, d = gth & 63;
    const int i = r & 1023, bh = r >> 10;
    const int b = bh >> 3, h = bh & 7;
    const int g = i >> 7;
    const int ns = g + 1;
    const size_t slot0 = (size_t)bh * NSLOT_BH + 64 * g * (g + 1)
                       + (size_t)(i & 127) * (g + 1);
    float mstar = -INFINITY, lstar = 0.f, ostar = 0.f;
    for (int s = 0; s < ns; s++) {
        const float mi = pm[slot0 + s];
        const float nm = fmaxf(mstar, mi);
        const float a = __expf(mstar - nm);
        const float w = __expf(mi - nm);
        lstar = lstar * a + pl[slot0 + s] * w;
        ostar = ostar * a + po[(slot0 + s) * 64 + d] * w;
        mstar = nm;
    }
    AO[((size_t)(b * S_ + i)) * D_ + h * DH_ + d] = ostar / lstar;
}

// ---------- projection via MFMA (bf16 hi/lo 3-term) + ploss fold -----------
__global__ __launch_bounds__(256) void proj_kernel(
    const float* __restrict__ A,
    const ushort* __restrict__ Wth, const ushort* __restrict__ Wtl,
    const float* __restrict__ acc,
    float* __restrict__ out, float* __restrict__ outp)
{
    if (blockIdx.x == 0 && threadIdx.x == 0) {
        float ssum = 0.f;
        for (int c = 0; c < 8; c++) {
            ssum += acc[c]      / (acc[8 + c]  + 1e-8f);
            ssum += acc[16 + c] / (acc[24 + c] + 1e-8f);
        }
        outp[0] = ssum * 0.125f;
    }
    const int tb = (blockIdx.x >> 4) * 64;   // 32 token tiles
    const int cb = (blockIdx.x & 15) * 32;   // 16 col tiles
    const int t = threadIdx.x, w = t >> 6, lane = t & 63;
    const int ln = lane & 15, ko = (lane >> 4) * 8;
    const int tok = tb + w * 16 + ln;

    const f32x4 fz = {0.f, 0.f, 0.f, 0.f};
    f32x4 acc2[2];
    acc2[0] = fz; acc2[1] = fz;

    const float* Ap = A + (size_t)tok * 512 + ko;
    #pragma unroll 4
    for (int ks = 0; ks < 512; ks += 32) {
        union { float4 f4[2]; float f[8]; } af;
        af.f4[0] = *(const float4*)(Ap + ks);
        af.f4[1] = *(const float4*)(Ap + ks + 4);
        union { short8 v; ushort u[8]; } ah, al;
        #pragma unroll
        for (int i = 0; i < 8; i++) {
            ah.u[i] = f2b_rn(af.f[i]);
            al.u[i] = f2b_rn(af.f[i] - b2f(ah.u[i]));
        }
        #pragma unroll
        for (int ct = 0; ct < 2; ct++) {
            const size_t wb = (size_t)(cb + ct * 16 + ln) * 512 + ks + ko;
            const short8 bh = *(const short8*)(Wth + wb);
            const short8 bl = *(const short8*)(Wtl + wb);
            acc2[ct] = __builtin_amdgcn_mfma_f32_16x16x32_bf16(ah.v, bh, acc2[ct], 0, 0, 0);
            acc2[ct] = __builtin_amdgcn_mfma_f32_16x16x32_bf16(al.v, bh, acc2[ct], 0, 0, 0);
            acc2[ct] = __builtin_amdgcn_mfma_f32_16x16x32_bf16(ah.v, bl, acc2[ct], 0, 0, 0);
        }
    }
    #pragma unroll
    for (int ct = 0; ct < 2; ct++) {
        #pragma unroll
        for (int r = 0; r < 4; r++) {
            const int row = tb + w * 16 + (lane >> 4) * 4 + r;
            out[(size_t)row * 512 + cb + ct * 16 + ln] = acc2[ct][r];
        }
    }
}

extern "C" void kernel_launch(void* const* d_in, const int* in_sizes, int n_in,
                              void* d_out, int out_size, void* d_ws, size_t ws_size,
                              hipStream_t stream) {
    const float* x          = (const float*)d_in[0];
    const float* qk_pos     = (const float*)d_in[1];
    const float* v_pos      = (const float*)d_in[2];
    const float* tauQ       = (const float*)d_in[3];
    const float* tauK       = (const float*)d_in[4];
    const float* tauV       = (const float*)d_in[5];
    const float* qk_neurons = (const float*)d_in[6];
    const float* v_neurons  = (const float*)d_in[7];
    const float* npos_qk    = (const float*)d_in[8];
    const float* npos_v     = (const float*)d_in[9];
    const int*   cm_qk      = (const int*)d_in[10];
    const int*   cm_v       = (const int*)d_in[11];
    const float* pos_min    = (const float*)d_in[12];
    const float* pos_range  = (const float*)d_in[13];
    const float* expand_O   = (const float*)d_in[14];

    float* ws = (float*)d_ws;
    const size_t TDf = (size_t)NTOK * D_;     // 1,048,576 floats
    float* Q   = ws;
    float* K   = ws + TDf;
    float* V   = ws + 2 * TDf;
    float* AO  = ws + 3 * TDf;
    float* acc = ws + 4 * TDf;                // 64 float slots
    int*   order_qk = (int*)(ws + 4 * TDf + 64);
    int*   order_v  = order_qk + NTOK;
    int2*  desc_qk  = (int2*)(order_v + NTOK);
    int2*  desc_v   = desc_qk + NG2;
    const size_t head = 4 * TDf + 64 + 2 * NTOK + 4 * NG2;  // float units

    float* pm = ws + head;                    // NSLOTS
    float* pl = pm + (size_t)NSLOTS;
    float* po = pl + (size_t)NSLOTS;          // NSLOTS*64
    ushort* Wth = (ushort*)(po + (size_t)NSLOTS * 64);   // 512*512 ushort
    ushort* Wtl = Wth + 512 * 512;
    ushort* nqh = Wtl + 512 * 512;            // 4096*512 each
    ushort* nql = nqh + (size_t)N_ * D_;
    ushort* nvh = nql + (size_t)N_ * D_;
    ushort* nvl = nvh + (size_t)N_ * D_;

    float* out = (float*)d_out;

    sort_wprep_kernel<<<322, 1024, 0, stream>>>(qk_pos, v_pos, pos_min, pos_range,
                                                order_qk, order_v, desc_qk, desc_v,
                                                acc, expand_O, Wth, Wtl,
                                                qk_neurons, v_neurons,
                                                nqh, nql, nvh, nvl);
    qkv_fused<<<2 * NG2, 256, 0, stream>>>(desc_qk, order_qk, desc_v, order_v,
                                           x, qk_pos, v_pos, tauQ, tauK, tauV,
                                           qk_neurons, v_neurons,
                                           nqh, nql, nvh, nvl,
                                           npos_qk, npos_v,
                                           cm_qk, cm_v, pos_min, pos_range,
                                           Q, K, V, acc);
    attn_partial_kernel<<<16 * 36, 256, 0, stream>>>(Q, K, V, pm, pl, po);
    attn_combine_kernel<<<(NROWS * 64) / 256, 256, 0, stream>>>(pm, pl, po, AO);
    proj_kernel<<<512, 256, 0, stream>>>(AO, Wth, Wtl, acc, out, out + TDf);
}

// Round 12
// 273.200 us; speedup vs baseline: 1.1841x; 1.1841x over previous
//
#include <hip/hip_runtime.h>
#include <math.h>

#define B_ 2
#define S_ 1024
#define D_ 512
#define N_ 4096
#define H_ 8
#define DH_ 64
#define NCAND 288   // 9 neighbor cells * 32 entries
#define TOPK 32
#define NTOK (B_*S_)   // 2048
#define NG2 1152       // max 2-token same-cell groups (8*144)

#define NROWS 16384       // B*H*S
#define NSLOT_BH 4608     // sum over rows i<1024 of (i/128+1)
#define NSLOTS (16*NSLOT_BH)

typedef __attribute__((ext_vector_type(8))) short short8;
typedef __attribute__((ext_vector_type(4))) float f32x4;

__device__ __forceinline__ float wave_sum(float v) {
    #pragma unroll
    for (int o = 32; o; o >>= 1) v += __shfl_xor(v, o);
    return v;
}
__device__ __forceinline__ float wave_max(float v) {
    #pragma unroll
    for (int o = 32; o; o >>= 1) v = fmaxf(v, __shfl_xor(v, o));
    return v;
}
__device__ __forceinline__ ushort f2b_rn(float f) {
    unsigned u = __float_as_uint(f);
    return (ushort)((u + 0x7FFFu + ((u >> 16) & 1u)) >> 16);
}
__device__ __forceinline__ float b2f(ushort h) {
    return __uint_as_float(((unsigned)h) << 16);
}
__device__ __forceinline__ int swzi(int row, int c8) {
    return row * 64 + ((c8 ^ (row & 7)) << 3);
}

// ---------- token sort (blocks 0-1) + W prep (blocks 2-65), fused ----------
__global__ __launch_bounds__(1024) void sort_wprep_kernel(
    const float* __restrict__ qk_pos, const float* __restrict__ v_pos,
    const float* __restrict__ pos_min, const float* __restrict__ pos_range,
    int* __restrict__ order_qk, int* __restrict__ order_v,
    int2* __restrict__ desc_qk, int2* __restrict__ desc_v,
    float* __restrict__ posacc,
    const float* __restrict__ W, ushort* __restrict__ Wth, ushort* __restrict__ Wtl)
{
    __shared__ int hist[256], tmp[256], offs[256], startc[256], gcnt[256];
    __shared__ float tile[64][65];
    const int t = threadIdx.x;
    const int bid = blockIdx.x;

    if (bid >= 2) {
        // ---- wprep: transpose + bf16 hi/lo split of expand_O ----
        const int bb = bid - 2;
        const int bx = bb & 7, by = bb >> 3;   // 8x8 tiles of 64x64
        if (t < 256) {
            const int r = t >> 4, c4 = (t & 15) * 4;
            #pragma unroll
            for (int rr = 0; rr < 64; rr += 16) {
                const float4 v = *(const float4*)(W + (size_t)(by * 64 + rr + r) * 512 + bx * 64 + c4);
                *(float4*)&tile[rr + r][c4] = v;            // tile[k][c]
            }
        }
        __syncthreads();
        if (t < 256) {
            const int r = t >> 4, c4 = (t & 15) * 4;
            #pragma unroll
            for (int cc = 0; cc < 64; cc += 16) {
                const int c = cc + r;
                ushort h[4], l[4];
                #pragma unroll
                for (int i = 0; i < 4; i++) {
                    float f = tile[c4 + i][c];
                    h[i] = f2b_rn(f);
                    l[i] = f2b_rn(f - b2f(h[i]));
                }
                *(uint2*)&Wth[(size_t)(bx * 64 + c) * 512 + by * 64 + c4] = *(uint2*)h;
                *(uint2*)&Wtl[(size_t)(bx * 64 + c) * 512 + by * 64 + c4] = *(uint2*)l;
            }
        }
        return;
    }

    // ---- sort pass ----
    const int pass = bid;
    if (pass == 0 && t < 32) posacc[t] = 0.f;
    const float pm0 = pos_min[0], pm1 = pos_min[1];
    const float pr0 = pos_range[0], pr1 = pos_range[1];
    const float* pos = pass ? v_pos : qk_pos;
    int* order = pass ? order_v : order_qk;
    int2* desc = pass ? desc_v : desc_qk;
    if (t < NG2) desc[t] = make_int2(0, 0);
    if (t + 1024 < NG2) desc[t + 1024] = make_int2(0, 0);
    if (t < 256) hist[t] = 0;
    __syncthreads();
    int cell[2];
    #pragma unroll
    for (int k = 0; k < 2; k++) {
        int tok = t + k * 1024;
        float p0 = pos[tok * 2], p1 = pos[tok * 2 + 1];
        int cx = min(max((int)((p0 - pm0) / pr0 * 16.f), 0), 15);
        int cy = min(max((int)((p1 - pm1) / pr1 * 16.f), 0), 15);
        cell[k] = cx * 16 + cy;
        atomicAdd(&hist[cell[k]], 1);
    }
    __syncthreads();
    if (t < 256) tmp[t] = hist[t];
    __syncthreads();
    for (int d = 1; d < 256; d <<= 1) {
        int v = 0;
        if (t < 256 && t >= d) v = tmp[t - d];
        __syncthreads();
        if (t < 256) tmp[t] += v;
        __syncthreads();
    }
    if (t < 256) {
        startc[t] = tmp[t] - hist[t];
        offs[t]   = startc[t];
        gcnt[t]   = (hist[t] + 1) >> 1;
    }
    __syncthreads();
    #pragma unroll
    for (int k = 0; k < 2; k++) {
        int tok = t + k * 1024;
        int p = atomicAdd(&offs[cell[k]], 1);
        order[p] = tok;
    }
    __syncthreads();
    if (t < 256) tmp[t] = gcnt[t];
    __syncthreads();
    for (int d = 1; d < 256; d <<= 1) {
        int v = 0;
        if (t < 256 && t >= d) v = tmp[t - d];
        __syncthreads();
        if (t < 256) tmp[t] += v;
        __syncthreads();
    }
    if (t < 256) {
        int g0 = tmp[t] - gcnt[t];
        for (int k = 0; k < gcnt[t]; k++)
            desc[g0 + k] = make_int2(startc[t] + 2 * k, min(2, hist[t] - 2 * k));
    }
}

// ---------- fused QK+V kernel (r1 body; launch_bounds(256,2) relaxes the ---
// VGPR cap from the default 8-wave/SIMD bin (<=64) to <=256 so xr0/xr1
// (64 VGPRs) can stay register-resident instead of being rematerialized
// from global inside the dot loop. VGPR_Count=60 < 64+~30 proved
// non-residency; occupancy measured ~10 waves/CU << the new 16 ceiling.
__global__ __launch_bounds__(256, 2) void qkv_fused(
    const int2* __restrict__ desc_qk, const int* __restrict__ order_qk,
    const int2* __restrict__ desc_v,  const int* __restrict__ order_v,
    const float* __restrict__ x,
    const float* __restrict__ qk_pos, const float* __restrict__ v_pos,
    const float* __restrict__ tauQ, const float* __restrict__ tauK,
    const float* __restrict__ tauV,
    const float* __restrict__ qk_neurons, const float* __restrict__ v_neurons,
    const float* __restrict__ npos_qk, const float* __restrict__ npos_v,
    const int* __restrict__ cm_qk, const int* __restrict__ cm_v,
    const float* __restrict__ pos_min, const float* __restrict__ pos_range,
    float* __restrict__ Q, float* __restrict__ K, float* __restrict__ V,
    float* __restrict__ posacc)
{
    const int bid = blockIdx.x;
    const int role = bid & 1;
    const int g = bid >> 1;
    const int gid = (g & 7) * 144 + (g >> 3);
    const int2 dsc = role ? desc_v[gid] : desc_qk[gid];
    const int gstart = dsc.x, count = dsc.y;
    if (count == 0) return;

    const int*   order   = role ? order_v   : order_qk;
    const float* pose    = role ? v_pos     : qk_pos;
    const float* neurons = role ? v_neurons : qk_neurons;
    const float* npos    = role ? npos_v    : npos_qk;
    const int*   cmap    = role ? cm_v      : cm_qk;

    __shared__ int   idx[NCAND];
    __shared__ float msk[NCAND];
    __shared__ float act[2][NCAND];
    __shared__ int   ci[2][NCAND];
    __shared__ float cw1[2][NCAND], cw2[2][NCAND];
    __shared__ int   toks[2], cnt2[2];
    __shared__ float red[2][2][4];
    __shared__ float redc;

    const int t = threadIdx.x, wid = t >> 6, lane = t & 63;
    const int sub = lane & 15, grp = lane >> 4;
    if (t < 2) { toks[t] = order[gstart + min(t, count - 1)]; cnt2[t] = 0; }
    __syncthreads();
    const int token0 = toks[0];

    const float pm0 = pos_min[0], pm1 = pos_min[1];
    const float pr0 = pos_range[0], pr1 = pos_range[1];
    {
        const float p0 = pose[token0 * 2], p1 = pose[token0 * 2 + 1];
        const int cx = min(max((int)((p0 - pm0) / pr0 * 16.f), 0), 15);
        const int cy = min(max((int)((p1 - pm1) / pr1 * 16.f), 0), 15);
        for (int c = t; c < NCAND; c += 256) {
            int o = c >> 5, ms = c & 31;
            int nx = min(max(cx + o / 3 - 1, 0), 15), ny = min(max(cy + o % 3 - 1, 0), 15);
            int cand = cmap[(nx * 16 + ny) * 32 + ms];
            idx[c] = cand >= 0 ? cand : 0;
            msk[c] = cand >= 0 ? 1.f : 0.f;
        }
    }
    __syncthreads();

    float4 xr0[8], xr1[8];
    {
        const float4* xp0 = (const float4*)(x + (size_t)toks[0] * D_);
        const float4* xp1 = (const float4*)(x + (size_t)toks[1] * D_);
        #pragma unroll
        for (int k = 0; k < 8; k++) {
            xr0[k] = xp0[k * 16 + sub];
            xr1[k] = xp1[k * 16 + sub];
        }
    }

    // --- dot phase: 16-lane groups, 4 candidates per wave-iteration ---
    const int cb = wid * 72;
    for (int u = 0; u < 72; u += 4) {
        const int c = cb + u + grp;
        const float4* rp = (const float4*)(neurons + (size_t)idx[c] * D_);
        float a0 = 0.f, a1 = 0.f, b0 = 0.f, b1 = 0.f;
        #pragma unroll
        for (int k = 0; k < 8; k += 2) {
            float4 r0 = rp[k * 16 + sub];
            float4 r1 = rp[(k + 1) * 16 + sub];
            a0 += xr0[k].x*r0.x + xr0[k].y*r0.y + xr0[k].z*r0.z + xr0[k].w*r0.w;
            a1 += xr1[k].x*r0.x + xr1[k].y*r0.y + xr1[k].z*r0.z + xr1[k].w*r0.w;
            b0 += xr0[k+1].x*r1.x + xr0[k+1].y*r1.y + xr0[k+1].z*r1.z + xr0[k+1].w*r1.w;
            b1 += xr1[k+1].x*r1.x + xr1[k+1].y*r1.y + xr1[k+1].z*r1.z + xr1[k+1].w*r1.w;
        }
        float f0 = a0 + b0, f1 = a1 + b1;
        #pragma unroll
        for (int o = 1; o <= 8; o <<= 1) {
            f0 += __shfl_xor(f0, o);
            f1 += __shfl_xor(f1, o);
        }
        if (sub == 0) {
            const float mv = msk[c];
            act[0][c] = (mv != 0.f) ? f0 : -1e9f;
            act[1][c] = (mv != 0.f) ? f1 : -1e9f;
        }
    }
    __syncthreads();

    const int tk = wid >> 1, sw = wid & 1, tt = t & 127;
    const int token = toks[tk];

    if (sw == 0) {
        unsigned ej[5];
        #pragma unroll
        for (int k = 0; k < 5; k++) {
            int j = lane + 64 * k;
            float f = (j < NCAND) ? act[tk][j] : -1e30f;
            unsigned uu = __float_as_uint(f);
            ej[k] = (uu & 0x80000000u) ? ~uu : (uu | 0x80000000u);
        }
        unsigned T = 0u;
        for (int bit = 31; bit >= 0; bit--) {
            const unsigned cand = T | (1u << bit);
            int c = 0;
            #pragma unroll
            for (int k = 0; k < 5; k++)
                c += __popcll(__ballot(ej[k] >= cand));
            if (c >= TOPK) T = cand;
        }
        int base = 0;
        const unsigned long long below = (lane == 0) ? 0ull
                                       : (~0ull >> (64 - lane));
        #pragma unroll
        for (int k = 0; k < 5; k++) {
            const unsigned long long mk2 = __ballot(ej[k] >= T);
            if (ej[k] >= T) {
                int pos = base + __popcll(mk2 & below);
                ci[tk][pos] = lane + 64 * k;
            }
            base += __popcll(mk2);
        }
        if (lane == 0) cnt2[tk] = base;
    }
    if (wid == 0) {
        float cmv = 0.f;
        for (int c = lane; c < NCAND; c += 64) cmv += msk[c];
        cmv = wave_sum(cmv);
        if (lane == 0) redc = cmv;
    }
    __syncthreads();
    const float cm = redc;
    const int n = cnt2[tk];

    if (role == 0) {
        const float tq = tauQ[token], tkk = tauK[token];
        float sQ = 0.f, sK = 0.f, mQ = 0.f, mK = 0.f;
        for (int p = tt; p < n; p += 128) {
            float s = act[tk][ci[tk][p]];
            float rq = s - tq;
            float gq = (rq > 0.f) ? rq : 1e-8f * __expf(rq);
            float egq = __expf(gq) - 1.f;
            float rk = s - tkk;
            float gk = (rk > 0.f) ? rk : 1e-8f * __expf(rk);
            float egk = __expf(gk) - 1.f;
            cw1[tk][p] = egq; cw2[tk][p] = egk;
            sQ += egq; sK += egk;
            mQ = fmaxf(mQ, egq); mK = fmaxf(mK, egk);
        }
        sQ = wave_sum(sQ); mQ = wave_max(mQ);
        sK = wave_sum(sK); mK = wave_max(mK);
        if (lane == 0) {
            red[tk][sw][0] = sQ; red[tk][sw][1] = mQ;
            red[tk][sw][2] = sK; red[tk][sw][3] = mK;
        }
        __syncthreads();
        const float scQ = tanhf(fmaxf(red[tk][0][1], red[tk][1][1]))
                        / (red[tk][0][0] + red[tk][1][0] + 1e-8f);
        const float scK = tanhf(fmaxf(red[tk][0][3], red[tk][1][3]))
                        / (red[tk][0][2] + red[tk][1][2] + 1e-8f);
        __syncthreads();

        const float qp0 = pose[token * 2], qp1 = pose[token * 2 + 1];
        float plq = 0.f;
        for (int p = tt; p < n; p += 128) {
            int e = ci[tk][p];
            int id = idx[e];
            float m = msk[e], a = act[tk][e];
            float gq = cw1[tk][p] * scQ;
            cw1[tk][p] = a * gq * m;
            cw2[tk][p] = a * cw2[tk][p] * scK * m;
            ci[tk][p] = id;
            float d0 = qp0 - npos[id * 2], d1 = qp1 - npos[id * 2 + 1];
            plq += gq * (d0 * d0 + d1 * d1) * m;
        }
        plq = wave_sum(plq);
        if (lane == 0) red[tk][sw][0] = plq;
        __syncthreads();
        if (tt == 0 && tk < count) {
            int chunk = (token & 1023) >> 7;
            atomicAdd(&posacc[chunk], red[tk][0][0] + red[tk][1][0]);
            atomicAdd(&posacc[8 + chunk], cm);
        }

        if (tk < count) {
            float4 qa = {0,0,0,0}, ka = {0,0,0,0};
            int p = 0;
            for (; p + 1 < n; p += 2) {
                const float4 rA = *(const float4*)(neurons + (size_t)ci[tk][p] * D_ + tt * 4);
                const float4 rB = *(const float4*)(neurons + (size_t)ci[tk][p + 1] * D_ + tt * 4);
                const float wA = cw1[tk][p], bA = cw2[tk][p];
                const float wB = cw1[tk][p + 1], bB = cw2[tk][p + 1];
                qa.x += wA * rA.x + wB * rB.x; qa.y += wA * rA.y + wB * rB.y;
                qa.z += wA * rA.z + wB * rB.z; qa.w += wA * rA.w + wB * rB.w;
                ka.x += bA * rA.x + bB * rB.x; ka.y += bA * rA.y + bB * rB.y;
                ka.z += bA * rA.z + bB * rB.z; ka.w += bA * rA.w + bB * rB.w;
            }
            if (p < n) {
                const float4 rA = *(const float4*)(neurons + (size_t)ci[tk][p] * D_ + tt * 4);
                const float wA = cw1[tk][p], bA = cw2[tk][p];
                qa.x += wA * rA.x; qa.y += wA * rA.y; qa.z += wA * rA.z; qa.w += wA * rA.w;
                ka.x += bA * rA.x; ka.y += bA * rA.y; ka.z += bA * rA.z; ka.w += bA * rA.w;
            }
            *(float4*)(Q + (size_t)token * D_ + tt * 4) = qa;
            *(float4*)(K + (size_t)token * D_ + tt * 4) = ka;
        }
    } else {
        const float tv = tauV[token];
        float sV = 0.f, mV = 0.f;
        for (int p = tt; p < n; p += 128) {
            float s = act[tk][ci[tk][p]];
            float rv = s - tv;
            float gv = (rv > 0.f) ? rv : 1e-8f * __expf(rv);
            float egv = __expf(gv) - 1.f;
            cw1[tk][p] = egv;
            sV += egv; mV = fmaxf(mV, egv);
        }
        sV = wave_sum(sV); mV = wave_max(mV);
        if (lane == 0) { red[tk][sw][0] = sV; red[tk][sw][1] = mV; }
        __syncthreads();
        const float scV = tanhf(fmaxf(red[tk][0][1], red[tk][1][1]))
                        / (red[tk][0][0] + red[tk][1][0] + 1e-8f);
        __syncthreads();

        const float vp0 = pose[token * 2], vp1 = pose[token * 2 + 1];
        float plv = 0.f;
        for (int p = tt; p < n; p += 128) {
            int e = ci[tk][p];
            int id = idx[e];
            float m = msk[e], a = act[tk][e];
            float gv = cw1[tk][p] * scV;
            cw1[tk][p] = a * gv * m;
            ci[tk][p] = id;
            float d0 = vp0 - npos[id * 2], d1 = vp1 - npos[id * 2 + 1];
            plv += gv * (d0 * d0 + d1 * d1) * m;
        }
        plv = wave_sum(plv);
        if (lane == 0) red[tk][sw][0] = plv;
        __syncthreads();
        if (tt == 0 && tk < count) {
            int chunk = (token & 1023) >> 7;
            atomicAdd(&posacc[16 + chunk], red[tk][0][0] + red[tk][1][0]);
            atomicAdd(&posacc[24 + chunk], cm);
        }

        if (tk < count) {
            float4 va = {0,0,0,0};
            int p = 0;
            for (; p + 1 < n; p += 2) {
                const float4 rA = *(const float4*)(neurons + (size_t)ci[tk][p] * D_ + tt * 4);
                const float4 rB = *(const float4*)(neurons + (size_t)ci[tk][p + 1] * D_ + tt * 4);
                const float wA = cw1[tk][p], wB = cw1[tk][p + 1];
                va.x += wA * rA.x + wB * rB.x; va.y += wA * rA.y + wB * rB.y;
                va.z += wA * rA.z + wB * rB.z; va.w += wA * rA.w + wB * rB.w;
            }
            if (p < n) {
                const float4 rA = *(const float4*)(neurons + (size_t)ci[tk][p] * D_ + tt * 4);
                const float wA = cw1[tk][p];
                va.x += wA * rA.x; va.y += wA * rA.y; va.z += wA * rA.z; va.w += wA * rA.w;
            }
            *(float4*)(V + (size_t)token * D_ + tt * 4) = va;
        }
    }
}

// ---------- MFMA attention partials: KV tile = 128 keys, in-block merge ----
__global__ __launch_bounds__(256, 2) void attn_partial_kernel(
    const float* __restrict__ Q, const float* __restrict__ K,
    const float* __restrict__ V,
    float* __restrict__ pm, float* __restrict__ pl, float* __restrict__ po)
{
    const int bh = blockIdx.x & 15;
    int kq = blockIdx.x >> 4;            // 0..35
    int rblk = 0;
    while (kq >= rblk + 1) { kq -= rblk + 1; rblk++; }
    const int sp = kq;                   // 0..rblk
    const int b = bh >> 3, h = bh & 7;
    const int j0 = sp * 128;
    const int rbase = rblk * 128;

    __shared__ __align__(16) ushort sKhi[64 * 64], sKlo[64 * 64];
    __shared__ __align__(16) ushort sVthi[64 * 64], sVtlo[64 * 64];
    __shared__ __align__(16) float sPool[8192];   // Vf fp32 [64][65] then P bounce

    const int t = threadIdx.x;
    const int w = t >> 6, lane = t & 63;
    const int g = lane >> 4, ln = lane & 15;
    const int wrow = rbase + w * 32;

    // ---- Q fragments in registers (bf16 hi/lo), loaded once ----
    short8 qhi[2][2], qlo[2][2];
    #pragma unroll
    for (int qt = 0; qt < 2; qt++) {
        const int qrow = wrow + qt * 16 + ln;
        const float* Qg = Q + ((size_t)(b * S_ + qrow)) * D_ + h * DH_ + g * 8;
        #pragma unroll
        for (int ds = 0; ds < 2; ds++) {
            union { float4 f4[2]; float f[8]; } qf;
            qf.f4[0] = *(const float4*)(Qg + ds * 32);
            qf.f4[1] = *(const float4*)(Qg + ds * 32 + 4);
            union { short8 v; ushort u[8]; } uh, ul;
            #pragma unroll
            for (int i = 0; i < 8; i++) {
                uh.u[i] = f2b_rn(qf.f[i]);
                ul.u[i] = f2b_rn(qf.f[i] - b2f(uh.u[i]));
            }
            qhi[qt][ds] = uh.v; qlo[qt][ds] = ul.v;
        }
    }

    const f32x4 fzero = {0.f, 0.f, 0.f, 0.f};
    f32x4 ot[4][2];
    #pragma unroll
    for (int dt = 0; dt < 4; dt++)
        #pragma unroll
        for (int qt = 0; qt < 2; qt++)
            ot[dt][qt] = fzero;
    float m_run[2] = {-1e30f, -1e30f};
    float l_run[2] = {0.f, 0.f};

    for (int half = 0; half < 2; half++) {
        const int j0h = j0 + half * 64;
        __syncthreads();   // protect LDS before restage

        {
            const int srow = t >> 2, scol = (t & 3) << 4;
            const float* Kg = K + ((size_t)(b * S_ + j0h + srow)) * D_ + h * DH_ + scol;
            const float* Vg = V + ((size_t)(b * S_ + j0h + srow)) * D_ + h * DH_ + scol;
            union { float4 f4[4]; float f[16]; } kf, vf;
            kf.f4[0] = *(const float4*)(Kg);
            kf.f4[1] = *(const float4*)(Kg + 4);
            kf.f4[2] = *(const float4*)(Kg + 8);
            kf.f4[3] = *(const float4*)(Kg + 12);
            vf.f4[0] = *(const float4*)(Vg);
            vf.f4[1] = *(const float4*)(Vg + 4);
            vf.f4[2] = *(const float4*)(Vg + 8);
            vf.f4[3] = *(const float4*)(Vg + 12);
            union { uint4 d[2]; ushort u[16]; } uh, ul;
            #pragma unroll
            for (int i = 0; i < 16; i++) {
                uh.u[i] = f2b_rn(kf.f[i]);
                ul.u[i] = f2b_rn(kf.f[i] - b2f(uh.u[i]));
            }
            const int c8 = (t & 3) << 1;
            *(uint4*)&sKhi[swzi(srow, c8)]     = uh.d[0];
            *(uint4*)&sKhi[swzi(srow, c8 + 1)] = uh.d[1];
            *(uint4*)&sKlo[swzi(srow, c8)]     = ul.d[0];
            *(uint4*)&sKlo[swzi(srow, c8 + 1)] = ul.d[1];
            #pragma unroll
            for (int i = 0; i < 16; i++) sPool[srow * 65 + scol + i] = vf.f[i];
        }
        __syncthreads();
        {
            const int drow = t >> 2, kcol = (t & 3) << 4;
            union { uint4 d[2]; ushort u[16]; } uh, ul;
            #pragma unroll
            for (int i = 0; i < 16; i++) {
                const float f = sPool[(kcol + i) * 65 + drow];
                uh.u[i] = f2b_rn(f);
                ul.u[i] = f2b_rn(f - b2f(uh.u[i]));
            }
            const int c8 = (t & 3) << 1;
            *(uint4*)&sVthi[swzi(drow, c8)]     = uh.d[0];
            *(uint4*)&sVthi[swzi(drow, c8 + 1)] = uh.d[1];
            *(uint4*)&sVtlo[swzi(drow, c8)]     = ul.d[0];
            *(uint4*)&sVtlo[swzi(drow, c8 + 1)] = ul.d[1];
        }
        __syncthreads();

        if (wrow + 31 < j0h) continue;

        ushort* sPw = (ushort*)sPool + w * 4096;

        f32x4 sT[2][4];
        #pragma unroll
        for (int qt = 0; qt < 2; qt++)
            #pragma unroll
            for (int kt = 0; kt < 4; kt++)
                sT[qt][kt] = fzero;
        #pragma unroll
        for (int ds = 0; ds < 2; ds++) {
            #pragma unroll
            for (int kt = 0; kt < 4; kt++) {
                const int krow = kt * 16 + ln;
                const short8 khi = *(const short8*)&sKhi[swzi(krow, ds * 4 + g)];
                const short8 klo = *(const short8*)&sKlo[swzi(krow, ds * 4 + g)];
                #pragma unroll
                for (int qt = 0; qt < 2; qt++) {
                    sT[qt][kt] = __builtin_amdgcn_mfma_f32_16x16x32_bf16(khi, qhi[qt][ds], sT[qt][kt], 0, 0, 0);
                    sT[qt][kt] = __builtin_amdgcn_mfma_f32_16x16x32_bf16(khi, qlo[qt][ds], sT[qt][kt], 0, 0, 0);
                    sT[qt][kt] = __builtin_amdgcn_mfma_f32_16x16x32_bf16(klo, qhi[qt][ds], sT[qt][kt], 0, 0, 0);
                }
            }
        }

        #pragma unroll
        for (int qt = 0; qt < 2; qt++) {
            const int qg = wrow + qt * 16 + ln;
            float pv[16];
            float mq = -1e30f;
            #pragma unroll
            for (int kt = 0; kt < 4; kt++)
                #pragma unroll
                for (int r = 0; r < 4; r++) {
                    const int kg = j0h + kt * 16 + g * 4 + r;
                    float s = sT[qt][kt][r] * 0.125f;
                    s = (kg <= qg) ? s : -1e30f;
                    pv[kt * 4 + r] = s;
                    mq = fmaxf(mq, s);
                }
            mq = fmaxf(mq, __shfl_xor(mq, 16));
            mq = fmaxf(mq, __shfl_xor(mq, 32));
            const float mN = fmaxf(m_run[qt], mq);
            const float base = (mN < -1e29f) ? 0.f : mN;
            const float a = __expf(m_run[qt] - mN);
            m_run[qt] = mN;
            float lq = 0.f;
            #pragma unroll
            for (int i = 0; i < 16; i++) {
                const float e = __expf(pv[i] - base);
                pv[i] = e;
                lq += e;
            }
            lq += __shfl_xor(lq, 16);
            lq += __shfl_xor(lq, 32);
            l_run[qt] = l_run[qt] * a + lq;
            #pragma unroll
            for (int dt = 0; dt < 4; dt++)
                ot[dt][qt] *= a;

            const int qrow = qt * 16 + ln;
            #pragma unroll
            for (int kt = 0; kt < 4; kt++) {
                union { uint2 d; ushort u[4]; } h4, l4;
                #pragma unroll
                for (int r = 0; r < 4; r++) {
                    const float f = pv[kt * 4 + r];
                    h4.u[r] = f2b_rn(f);
                    l4.u[r] = f2b_rn(f - b2f(h4.u[r]));
                }
                const int c8 = kt * 2 + (g >> 1);
                const int idx = qrow * 64 + ((c8 ^ (qrow & 7)) << 3) + ((g & 1) << 2);
                *(uint2*)&sPw[idx] = h4.d;
                *(uint2*)&sPw[2048 + idx] = l4.d;
            }
        }

        #pragma unroll
        for (int ks = 0; ks < 2; ks++) {
            short8 pfh[2], pfl[2];
            #pragma unroll
            for (int qt = 0; qt < 2; qt++) {
                const int qrow = qt * 16 + ln;
                const int idx = qrow * 64 + (((ks * 4 + g) ^ (qrow & 7)) << 3);
                pfh[qt] = *(const short8*)&sPw[idx];
                pfl[qt] = *(const short8*)&sPw[2048 + idx];
            }
            #pragma unroll
            for (int dt = 0; dt < 4; dt++) {
                const int drow = dt * 16 + ln;
                const short8 vh = *(const short8*)&sVthi[swzi(drow, ks * 4 + g)];
                const short8 vl = *(const short8*)&sVtlo[swzi(drow, ks * 4 + g)];
                #pragma unroll
                for (int qt = 0; qt < 2; qt++) {
                    ot[dt][qt] = __builtin_amdgcn_mfma_f32_16x16x32_bf16(vh, pfh[qt], ot[dt][qt], 0, 0, 0);
                    ot[dt][qt] = __builtin_amdgcn_mfma_f32_16x16x32_bf16(vh, pfl[qt], ot[dt][qt], 0, 0, 0);
                    ot[dt][qt] = __builtin_amdgcn_mfma_f32_16x16x32_bf16(vl, pfh[qt], ot[dt][qt], 0, 0, 0);
                }
            }
        }
    }

    #pragma unroll
    for (int qt = 0; qt < 2; qt++) {
        const int qg = wrow + qt * 16 + ln;
        const int g2 = qg >> 7;                     // == rblk
        const size_t slot = (size_t)bh * NSLOT_BH + 64 * g2 * (g2 + 1)
                          + (size_t)(qg & 127) * (g2 + 1) + sp;
        if (g == 0) { pm[slot] = m_run[qt]; pl[slot] = l_run[qt]; }
        float* od = po + slot * 64 + g * 4;
        #pragma unroll
        for (int dt = 0; dt < 4; dt++)
            *(f32x4*)(od + dt * 16) = ot[dt][qt];
    }
}

// ---------- merge split partials (single-pass online merge) ----------
__global__ __launch_bounds__(256) void attn_combine_kernel(
    const float* __restrict__ pm, const float* __restrict__ pl,
    const float* __restrict__ po, float* __restrict__ AO)
{
    const int gth = blockIdx.x * 256 + threadIdx.x;
    const int r = gth >> 6, d = gth & 63;
    const int i = r & 1023, bh = r >> 10;
    const int b = bh >> 3, h = bh & 7;
    const int g = i >> 7;
    const int ns = g + 1;
    const size_t slot0 = (size_t)bh * NSLOT_BH + 64 * g * (g + 1)
                       + (size_t)(i & 127) * (g + 1);
    float mstar = -INFINITY, lstar = 0.f, ostar = 0.f;
    for (int s = 0; s < ns; s++) {
        const float mi = pm[slot0 + s];
        const float nm = fmaxf(mstar, mi);
        const float a = __expf(mstar - nm);
        const float w = __expf(mi - nm);
        lstar = lstar * a + pl[slot0 + s] * w;
        ostar = ostar * a + po[(slot0 + s) * 64 + d] * w;
        mstar = nm;
    }
    AO[((size_t)(b * S_ + i)) * D_ + h * DH_ + d] = ostar / lstar;
}

// ---------- projection via MFMA (bf16 hi/lo 3-term) + ploss fold -----------
__global__ __launch_bounds__(256) void proj_kernel(
    const float* __restrict__ A,
    const ushort* __restrict__ Wth, const ushort* __restrict__ Wtl,
    const float* __restrict__ acc,
    float* __restrict__ out, float* __restrict__ outp)
{
    if (blockIdx.x == 0 && threadIdx.x == 0) {
        float ssum = 0.f;
        for (int c = 0; c < 8; c++) {
            ssum += acc[c]      / (acc[8 + c]  + 1e-8f);
            ssum += acc[16 + c] / (acc[24 + c] + 1e-8f);
        }
        outp[0] = ssum * 0.125f;
    }
    const int tb = (blockIdx.x >> 4) * 64;   // 32 token tiles
    const int cb = (blockIdx.x & 15) * 32;   // 16 col tiles
    const int t = threadIdx.x, w = t >> 6, lane = t & 63;
    const int ln = lane & 15, ko = (lane >> 4) * 8;
    const int tok = tb + w * 16 + ln;

    const f32x4 fz = {0.f, 0.f, 0.f, 0.f};
    f32x4 acc2[2];
    acc2[0] = fz; acc2[1] = fz;

    const float* Ap = A + (size_t)tok * 512 + ko;
    #pragma unroll 4
    for (int ks = 0; ks < 512; ks += 32) {
        union { float4 f4[2]; float f[8]; } af;
        af.f4[0] = *(const float4*)(Ap + ks);
        af.f4[1] = *(const float4*)(Ap + ks + 4);
        union { short8 v; ushort u[8]; } ah, al;
        #pragma unroll
        for (int i = 0; i < 8; i++) {
            ah.u[i] = f2b_rn(af.f[i]);
            al.u[i] = f2b_rn(af.f[i] - b2f(ah.u[i]));
        }
        #pragma unroll
        for (int ct = 0; ct < 2; ct++) {
            const size_t wb = (size_t)(cb + ct * 16 + ln) * 512 + ks + ko;
            const short8 bh = *(const short8*)(Wth + wb);
            const short8 bl = *(const short8*)(Wtl + wb);
            acc2[ct] = __builtin_amdgcn_mfma_f32_16x16x32_bf16(ah.v, bh, acc2[ct], 0, 0, 0);
            acc2[ct] = __builtin_amdgcn_mfma_f32_16x16x32_bf16(al.v, bh, acc2[ct], 0, 0, 0);
            acc2[ct] = __builtin_amdgcn_mfma_f32_16x16x32_bf16(ah.v, bl, acc2[ct], 0, 0, 0);
        }
    }
    #pragma unroll
    for (int ct = 0; ct < 2; ct++) {
        #pragma unroll
        for (int r = 0; r < 4; r++) {
            const int row = tb + w * 16 + (lane >> 4) * 4 + r;
            out[(size_t)row * 512 + cb + ct * 16 + ln] = acc2[ct][r];
        }
    }
}

extern "C" void kernel_launch(void* const* d_in, const int* in_sizes, int n_in,
                              void* d_out, int out_size, void* d_ws, size_t ws_size,
                              hipStream_t stream) {
    const float* x          = (const float*)d_in[0];
    const float* qk_pos     = (const float*)d_in[1];
    const float* v_pos      = (const float*)d_in[2];
    const float* tauQ       = (const float*)d_in[3];
    const float* tauK       = (const float*)d_in[4];
    const float* tauV       = (const float*)d_in[5];
    const float* qk_neurons = (const float*)d_in[6];
    const float* v_neurons  = (const float*)d_in[7];
    const float* npos_qk    = (const float*)d_in[8];
    const float* npos_v     = (const float*)d_in[9];
    const int*   cm_qk      = (const int*)d_in[10];
    const int*   cm_v       = (const int*)d_in[11];
    const float* pos_min    = (const float*)d_in[12];
    const float* pos_range  = (const float*)d_in[13];
    const float* expand_O   = (const float*)d_in[14];

    float* ws = (float*)d_ws;
    const size_t TDf = (size_t)NTOK * D_;     // 1,048,576 floats
    float* Q   = ws;
    float* K   = ws + TDf;
    float* V   = ws + 2 * TDf;
    float* AO  = ws + 3 * TDf;
    float* acc = ws + 4 * TDf;                // 64 float slots
    int*   order_qk = (int*)(ws + 4 * TDf + 64);
    int*   order_v  = order_qk + NTOK;
    int2*  desc_qk  = (int2*)(order_v + NTOK);
    int2*  desc_v   = desc_qk + NG2;
    const size_t head = 4 * TDf + 64 + 2 * NTOK + 4 * NG2;  // float units

    float* pm = ws + head;                    // NSLOTS
    float* pl = pm + (size_t)NSLOTS;
    float* po = pl + (size_t)NSLOTS;          // NSLOTS*64
    ushort* Wth = (ushort*)(po + (size_t)NSLOTS * 64);   // 512*512 ushort
    ushort* Wtl = Wth + 512 * 512;

    float* out = (float*)d_out;

    sort_wprep_kernel<<<66, 1024, 0, stream>>>(qk_pos, v_pos, pos_min, pos_range,
                                               order_qk, order_v, desc_qk, desc_v,
                                               acc, expand_O, Wth, Wtl);
    qkv_fused<<<2 * NG2, 256, 0, stream>>>(desc_qk, order_qk, desc_v, order_v,
                                           x, qk_pos, v_pos, tauQ, tauK, tauV,
                                           qk_neurons, v_neurons, npos_qk, npos_v,
                                           cm_qk, cm_v, pos_min, pos_range,
                                           Q, K, V, acc);
    attn_partial_kernel<<<16 * 36, 256, 0, stream>>>(Q, K, V, pm, pl, po);
    attn_combine_kernel<<<(NROWS * 64) / 256, 256, 0, stream>>>(pm, pl, po, AO);
    proj_kernel<<<512, 256, 0, stream>>>(AO, Wth, Wtl, acc, out, out + TDf);
}

// Round 13
// 246.382 us; speedup vs baseline: 1.3130x; 1.1088x over previous
//
#include <hip/hip_runtime.h>
#include <math.h>

#define B_ 2
#define S_ 1024
#define D_ 512
#define N_ 4096
#define H_ 8
#define DH_ 64
#define NCAND 288   // 9 neighbor cells * 32 entries
#define TOPK 32
#define NTOK (B_*S_)   // 2048
#define NG2 1152       // max 2-token same-cell groups (8*144)

#define NROWS 16384       // B*H*S
#define NSLOT_BH 4608     // sum over rows i<1024 of (i/128+1)
#define NSLOTS (16*NSLOT_BH)

typedef __attribute__((ext_vector_type(8))) short short8;
typedef __attribute__((ext_vector_type(4))) float f32x4;

__device__ __forceinline__ float wave_sum(float v) {
    #pragma unroll
    for (int o = 32; o; o >>= 1) v += __shfl_xor(v, o);
    return v;
}
__device__ __forceinline__ float wave_max(float v) {
    #pragma unroll
    for (int o = 32; o; o >>= 1) v = fmaxf(v, __shfl_xor(v, o));
    return v;
}
__device__ __forceinline__ ushort f2b_rn(float f) {
    unsigned u = __float_as_uint(f);
    return (ushort)((u + 0x7FFFu + ((u >> 16) & 1u)) >> 16);
}
__device__ __forceinline__ float b2f(ushort h) {
    return __uint_as_float(((unsigned)h) << 16);
}
__device__ __forceinline__ int swzi(int row, int c8) {
    return row * 64 + ((c8 ^ (row & 7)) << 3);
}

// ---------- token sort (blocks 0-1) + W prep (blocks 2-65), fused ----------
__global__ __launch_bounds__(1024) void sort_wprep_kernel(
    const float* __restrict__ qk_pos, const float* __restrict__ v_pos,
    const float* __restrict__ pos_min, const float* __restrict__ pos_range,
    int* __restrict__ order_qk, int* __restrict__ order_v,
    int2* __restrict__ desc_qk, int2* __restrict__ desc_v,
    float* __restrict__ posacc,
    const float* __restrict__ W, ushort* __restrict__ Wth, ushort* __restrict__ Wtl)
{
    __shared__ int hist[256], tmp[256], offs[256], startc[256], gcnt[256];
    __shared__ float tile[64][65];
    const int t = threadIdx.x;
    const int bid = blockIdx.x;

    if (bid >= 2) {
        // ---- wprep: transpose + bf16 hi/lo split of expand_O ----
        const int bb = bid - 2;
        const int bx = bb & 7, by = bb >> 3;   // 8x8 tiles of 64x64
        if (t < 256) {
            const int r = t >> 4, c4 = (t & 15) * 4;
            #pragma unroll
            for (int rr = 0; rr < 64; rr += 16) {
                const float4 v = *(const float4*)(W + (size_t)(by * 64 + rr + r) * 512 + bx * 64 + c4);
                *(float4*)&tile[rr + r][c4] = v;            // tile[k][c]
            }
        }
        __syncthreads();
        if (t < 256) {
            const int r = t >> 4, c4 = (t & 15) * 4;
            #pragma unroll
            for (int cc = 0; cc < 64; cc += 16) {
                const int c = cc + r;
                ushort h[4], l[4];
                #pragma unroll
                for (int i = 0; i < 4; i++) {
                    float f = tile[c4 + i][c];
                    h[i] = f2b_rn(f);
                    l[i] = f2b_rn(f - b2f(h[i]));
                }
                *(uint2*)&Wth[(size_t)(bx * 64 + c) * 512 + by * 64 + c4] = *(uint2*)h;
                *(uint2*)&Wtl[(size_t)(bx * 64 + c) * 512 + by * 64 + c4] = *(uint2*)l;
            }
        }
        return;
    }

    // ---- sort pass ----
    const int pass = bid;
    if (pass == 0 && t < 32) posacc[t] = 0.f;
    const float pm0 = pos_min[0], pm1 = pos_min[1];
    const float pr0 = pos_range[0], pr1 = pos_range[1];
    const float* pos = pass ? v_pos : qk_pos;
    int* order = pass ? order_v : order_qk;
    int2* desc = pass ? desc_v : desc_qk;
    if (t < NG2) desc[t] = make_int2(0, 0);
    if (t + 1024 < NG2) desc[t + 1024] = make_int2(0, 0);
    if (t < 256) hist[t] = 0;
    __syncthreads();
    int cell[2];
    #pragma unroll
    for (int k = 0; k < 2; k++) {
        int tok = t + k * 1024;
        float p0 = pos[tok * 2], p1 = pos[tok * 2 + 1];
        int cx = min(max((int)((p0 - pm0) / pr0 * 16.f), 0), 15);
        int cy = min(max((int)((p1 - pm1) / pr1 * 16.f), 0), 15);
        cell[k] = cx * 16 + cy;
        atomicAdd(&hist[cell[k]], 1);
    }
    __syncthreads();
    if (t < 256) tmp[t] = hist[t];
    __syncthreads();
    for (int d = 1; d < 256; d <<= 1) {
        int v = 0;
        if (t < 256 && t >= d) v = tmp[t - d];
        __syncthreads();
        if (t < 256) tmp[t] += v;
        __syncthreads();
    }
    if (t < 256) {
        startc[t] = tmp[t] - hist[t];
        offs[t]   = startc[t];
        gcnt[t]   = (hist[t] + 1) >> 1;
    }
    __syncthreads();
    #pragma unroll
    for (int k = 0; k < 2; k++) {
        int tok = t + k * 1024;
        int p = atomicAdd(&offs[cell[k]], 1);
        order[p] = tok;
    }
    __syncthreads();
    if (t < 256) tmp[t] = gcnt[t];
    __syncthreads();
    for (int d = 1; d < 256; d <<= 1) {
        int v = 0;
        if (t < 256 && t >= d) v = tmp[t - d];
        __syncthreads();
        if (t < 256) tmp[t] += v;
        __syncthreads();
    }
    if (t < 256) {
        int g0 = tmp[t] - gcnt[t];
        for (int k = 0; k < gcnt[t]; k++)
            desc[g0 + k] = make_int2(startc[t] + 2 * k, min(2, hist[t] - 2 * k));
    }
}

// ---------- fused QK+V kernel (r1/r10 body, verbatim: measured ~106 us) ----
// NOTE: no __launch_bounds__ min-occupancy arg. Nine attempts to beat or
// re-schedule this kernel (r2-r7 structure, r9 epilogue, r11 MFMA, r12
// launch_bounds) all regressed; the default compiler schedule is a local
// optimum for this body.
__global__ __launch_bounds__(256) void qkv_fused(
    const int2* __restrict__ desc_qk, const int* __restrict__ order_qk,
    const int2* __restrict__ desc_v,  const int* __restrict__ order_v,
    const float* __restrict__ x,
    const float* __restrict__ qk_pos, const float* __restrict__ v_pos,
    const float* __restrict__ tauQ, const float* __restrict__ tauK,
    const float* __restrict__ tauV,
    const float* __restrict__ qk_neurons, const float* __restrict__ v_neurons,
    const float* __restrict__ npos_qk, const float* __restrict__ npos_v,
    const int* __restrict__ cm_qk, const int* __restrict__ cm_v,
    const float* __restrict__ pos_min, const float* __restrict__ pos_range,
    float* __restrict__ Q, float* __restrict__ K, float* __restrict__ V,
    float* __restrict__ posacc)
{
    const int bid = blockIdx.x;
    const int role = bid & 1;
    const int g = bid >> 1;
    const int gid = (g & 7) * 144 + (g >> 3);
    const int2 dsc = role ? desc_v[gid] : desc_qk[gid];
    const int gstart = dsc.x, count = dsc.y;
    if (count == 0) return;

    const int*   order   = role ? order_v   : order_qk;
    const float* pose    = role ? v_pos     : qk_pos;
    const float* neurons = role ? v_neurons : qk_neurons;
    const float* npos    = role ? npos_v    : npos_qk;
    const int*   cmap    = role ? cm_v      : cm_qk;

    __shared__ int   idx[NCAND];
    __shared__ float msk[NCAND];
    __shared__ float act[2][NCAND];
    __shared__ int   ci[2][NCAND];
    __shared__ float cw1[2][NCAND], cw2[2][NCAND];
    __shared__ int   toks[2], cnt2[2];
    __shared__ float red[2][2][4];
    __shared__ float redc;

    const int t = threadIdx.x, wid = t >> 6, lane = t & 63;
    const int sub = lane & 15, grp = lane >> 4;
    if (t < 2) { toks[t] = order[gstart + min(t, count - 1)]; cnt2[t] = 0; }
    __syncthreads();
    const int token0 = toks[0];

    const float pm0 = pos_min[0], pm1 = pos_min[1];
    const float pr0 = pos_range[0], pr1 = pos_range[1];
    {
        const float p0 = pose[token0 * 2], p1 = pose[token0 * 2 + 1];
        const int cx = min(max((int)((p0 - pm0) / pr0 * 16.f), 0), 15);
        const int cy = min(max((int)((p1 - pm1) / pr1 * 16.f), 0), 15);
        for (int c = t; c < NCAND; c += 256) {
            int o = c >> 5, ms = c & 31;
            int nx = min(max(cx + o / 3 - 1, 0), 15), ny = min(max(cy + o % 3 - 1, 0), 15);
            int cand = cmap[(nx * 16 + ny) * 32 + ms];
            idx[c] = cand >= 0 ? cand : 0;
            msk[c] = cand >= 0 ? 1.f : 0.f;
        }
    }
    __syncthreads();

    float4 xr0[8], xr1[8];
    {
        const float4* xp0 = (const float4*)(x + (size_t)toks[0] * D_);
        const float4* xp1 = (const float4*)(x + (size_t)toks[1] * D_);
        #pragma unroll
        for (int k = 0; k < 8; k++) {
            xr0[k] = xp0[k * 16 + sub];
            xr1[k] = xp1[k * 16 + sub];
        }
    }

    // --- dot phase: 16-lane groups, 4 candidates per wave-iteration ---
    const int cb = wid * 72;
    for (int u = 0; u < 72; u += 4) {
        const int c = cb + u + grp;
        const float4* rp = (const float4*)(neurons + (size_t)idx[c] * D_);
        float a0 = 0.f, a1 = 0.f, b0 = 0.f, b1 = 0.f;
        #pragma unroll
        for (int k = 0; k < 8; k += 2) {
            float4 r0 = rp[k * 16 + sub];
            float4 r1 = rp[(k + 1) * 16 + sub];
            a0 += xr0[k].x*r0.x + xr0[k].y*r0.y + xr0[k].z*r0.z + xr0[k].w*r0.w;
            a1 += xr1[k].x*r0.x + xr1[k].y*r0.y + xr1[k].z*r0.z + xr1[k].w*r0.w;
            b0 += xr0[k+1].x*r1.x + xr0[k+1].y*r1.y + xr0[k+1].z*r1.z + xr0[k+1].w*r1.w;
            b1 += xr1[k+1].x*r1.x + xr1[k+1].y*r1.y + xr1[k+1].z*r1.z + xr1[k+1].w*r1.w;
        }
        float f0 = a0 + b0, f1 = a1 + b1;
        #pragma unroll
        for (int o = 1; o <= 8; o <<= 1) {
            f0 += __shfl_xor(f0, o);
            f1 += __shfl_xor(f1, o);
        }
        if (sub == 0) {
            const float mv = msk[c];
            act[0][c] = (mv != 0.f) ? f0 : -1e9f;
            act[1][c] = (mv != 0.f) ? f1 : -1e9f;
        }
    }
    __syncthreads();

    const int tk = wid >> 1, sw = wid & 1, tt = t & 127;
    const int token = toks[tk];

    if (sw == 0) {
        unsigned ej[5];
        #pragma unroll
        for (int k = 0; k < 5; k++) {
            int j = lane + 64 * k;
            float f = (j < NCAND) ? act[tk][j] : -1e30f;
            unsigned uu = __float_as_uint(f);
            ej[k] = (uu & 0x80000000u) ? ~uu : (uu | 0x80000000u);
        }
        unsigned T = 0u;
        for (int bit = 31; bit >= 0; bit--) {
            const unsigned cand = T | (1u << bit);
            int c = 0;
            #pragma unroll
            for (int k = 0; k < 5; k++)
                c += __popcll(__ballot(ej[k] >= cand));
            if (c >= TOPK) T = cand;
        }
        int base = 0;
        const unsigned long long below = (lane == 0) ? 0ull
                                       : (~0ull >> (64 - lane));
        #pragma unroll
        for (int k = 0; k < 5; k++) {
            const unsigned long long mk2 = __ballot(ej[k] >= T);
            if (ej[k] >= T) {
                int pos = base + __popcll(mk2 & below);
                ci[tk][pos] = lane + 64 * k;
            }
            base += __popcll(mk2);
        }
        if (lane == 0) cnt2[tk] = base;
    }
    if (wid == 0) {
        float cmv = 0.f;
        for (int c = lane; c < NCAND; c += 64) cmv += msk[c];
        cmv = wave_sum(cmv);
        if (lane == 0) redc = cmv;
    }
    __syncthreads();
    const float cm = redc;
    const int n = cnt2[tk];

    if (role == 0) {
        const float tq = tauQ[token], tkk = tauK[token];
        float sQ = 0.f, sK = 0.f, mQ = 0.f, mK = 0.f;
        for (int p = tt; p < n; p += 128) {
            float s = act[tk][ci[tk][p]];
            float rq = s - tq;
            float gq = (rq > 0.f) ? rq : 1e-8f * __expf(rq);
            float egq = __expf(gq) - 1.f;
            float rk = s - tkk;
            float gk = (rk > 0.f) ? rk : 1e-8f * __expf(rk);
            float egk = __expf(gk) - 1.f;
            cw1[tk][p] = egq; cw2[tk][p] = egk;
            sQ += egq; sK += egk;
            mQ = fmaxf(mQ, egq); mK = fmaxf(mK, egk);
        }
        sQ = wave_sum(sQ); mQ = wave_max(mQ);
        sK = wave_sum(sK); mK = wave_max(mK);
        if (lane == 0) {
            red[tk][sw][0] = sQ; red[tk][sw][1] = mQ;
            red[tk][sw][2] = sK; red[tk][sw][3] = mK;
        }
        __syncthreads();
        const float scQ = tanhf(fmaxf(red[tk][0][1], red[tk][1][1]))
                        / (red[tk][0][0] + red[tk][1][0] + 1e-8f);
        const float scK = tanhf(fmaxf(red[tk][0][3], red[tk][1][3]))
                        / (red[tk][0][2] + red[tk][1][2] + 1e-8f);
        __syncthreads();

        const float qp0 = pose[token * 2], qp1 = pose[token * 2 + 1];
        float plq = 0.f;
        for (int p = tt; p < n; p += 128) {
            int e = ci[tk][p];
            int id = idx[e];
            float m = msk[e], a = act[tk][e];
            float gq = cw1[tk][p] * scQ;
            cw1[tk][p] = a * gq * m;
            cw2[tk][p] = a * cw2[tk][p] * scK * m;
            ci[tk][p] = id;
            float d0 = qp0 - npos[id * 2], d1 = qp1 - npos[id * 2 + 1];
            plq += gq * (d0 * d0 + d1 * d1) * m;
        }
        plq = wave_sum(plq);
        if (lane == 0) red[tk][sw][0] = plq;
        __syncthreads();
        if (tt == 0 && tk < count) {
            int chunk = (token & 1023) >> 7;
            atomicAdd(&posacc[chunk], red[tk][0][0] + red[tk][1][0]);
            atomicAdd(&posacc[8 + chunk], cm);
        }

        if (tk < count) {
            float4 qa = {0,0,0,0}, ka = {0,0,0,0};
            int p = 0;
            for (; p + 1 < n; p += 2) {
                const float4 rA = *(const float4*)(neurons + (size_t)ci[tk][p] * D_ + tt * 4);
                const float4 rB = *(const float4*)(neurons + (size_t)ci[tk][p + 1] * D_ + tt * 4);
                const float wA = cw1[tk][p], bA = cw2[tk][p];
                const float wB = cw1[tk][p + 1], bB = cw2[tk][p + 1];
                qa.x += wA * rA.x + wB * rB.x; qa.y += wA * rA.y + wB * rB.y;
                qa.z += wA * rA.z + wB * rB.z; qa.w += wA * rA.w + wB * rB.w;
                ka.x += bA * rA.x + bB * rB.x; ka.y += bA * rA.y + bB * rB.y;
                ka.z += bA * rA.z + bB * rB.z; ka.w += bA * rA.w + bB * rB.w;
            }
            if (p < n) {
                const float4 rA = *(const float4*)(neurons + (size_t)ci[tk][p] * D_ + tt * 4);
                const float wA = cw1[tk][p], bA = cw2[tk][p];
                qa.x += wA * rA.x; qa.y += wA * rA.y; qa.z += wA * rA.z; qa.w += wA * rA.w;
                ka.x += bA * rA.x; ka.y += bA * rA.y; ka.z += bA * rA.z; ka.w += bA * rA.w;
            }
            *(float4*)(Q + (size_t)token * D_ + tt * 4) = qa;
            *(float4*)(K + (size_t)token * D_ + tt * 4) = ka;
        }
    } else {
        const float tv = tauV[token];
        float sV = 0.f, mV = 0.f;
        for (int p = tt; p < n; p += 128) {
            float s = act[tk][ci[tk][p]];
            float rv = s - tv;
            float gv = (rv > 0.f) ? rv : 1e-8f * __expf(rv);
            float egv = __expf(gv) - 1.f;
            cw1[tk][p] = egv;
            sV += egv; mV = fmaxf(mV, egv);
        }
        sV = wave_sum(sV); mV = wave_max(mV);
        if (lane == 0) { red[tk][sw][0] = sV; red[tk][sw][1] = mV; }
        __syncthreads();
        const float scV = tanhf(fmaxf(red[tk][0][1], red[tk][1][1]))
                        / (red[tk][0][0] + red[tk][1][0] + 1e-8f);
        __syncthreads();

        const float vp0 = pose[token * 2], vp1 = pose[token * 2 + 1];
        float plv = 0.f;
        for (int p = tt; p < n; p += 128) {
            int e = ci[tk][p];
            int id = idx[e];
            float m = msk[e], a = act[tk][e];
            float gv = cw1[tk][p] * scV;
            cw1[tk][p] = a * gv * m;
            ci[tk][p] = id;
            float d0 = vp0 - npos[id * 2], d1 = vp1 - npos[id * 2 + 1];
            plv += gv * (d0 * d0 + d1 * d1) * m;
        }
        plv = wave_sum(plv);
        if (lane == 0) red[tk][sw][0] = plv;
        __syncthreads();
        if (tt == 0 && tk < count) {
            int chunk = (token & 1023) >> 7;
            atomicAdd(&posacc[16 + chunk], red[tk][0][0] + red[tk][1][0]);
            atomicAdd(&posacc[24 + chunk], cm);
        }

        if (tk < count) {
            float4 va = {0,0,0,0};
            int p = 0;
            for (; p + 1 < n; p += 2) {
                const float4 rA = *(const float4*)(neurons + (size_t)ci[tk][p] * D_ + tt * 4);
                const float4 rB = *(const float4*)(neurons + (size_t)ci[tk][p + 1] * D_ + tt * 4);
                const float wA = cw1[tk][p], wB = cw1[tk][p + 1];
                va.x += wA * rA.x + wB * rB.x; va.y += wA * rA.y + wB * rB.y;
                va.z += wA * rA.z + wB * rB.z; va.w += wA * rA.w + wB * rB.w;
            }
            if (p < n) {
                const float4 rA = *(const float4*)(neurons + (size_t)ci[tk][p] * D_ + tt * 4);
                const float wA = cw1[tk][p];
                va.x += wA * rA.x; va.y += wA * rA.y; va.z += wA * rA.z; va.w += wA * rA.w;
            }
            *(float4*)(V + (size_t)token * D_ + tt * 4) = va;
        }
    }
}

// ---------- MFMA attention partials: KV tile = 128 keys, in-block merge ----
__global__ __launch_bounds__(256, 2) void attn_partial_kernel(
    const float* __restrict__ Q, const float* __restrict__ K,
    const float* __restrict__ V,
    float* __restrict__ pm, float* __restrict__ pl, float* __restrict__ po)
{
    const int bh = blockIdx.x & 15;
    int kq = blockIdx.x >> 4;            // 0..35
    int rblk = 0;
    while (kq >= rblk + 1) { kq -= rblk + 1; rblk++; }
    const int sp = kq;                   // 0..rblk
    const int b = bh >> 3, h = bh & 7;
    const int j0 = sp * 128;
    const int rbase = rblk * 128;

    __shared__ __align__(16) ushort sKhi[64 * 64], sKlo[64 * 64];
    __shared__ __align__(16) ushort sVthi[64 * 64], sVtlo[64 * 64];
    __shared__ __align__(16) float sPool[8192];   // Vf fp32 [64][65] then P bounce

    const int t = threadIdx.x;
    const int w = t >> 6, lane = t & 63;
    const int g = lane >> 4, ln = lane & 15;
    const int wrow = rbase + w * 32;

    // ---- Q fragments in registers (bf16 hi/lo), loaded once ----
    short8 qhi[2][2], qlo[2][2];
    #pragma unroll
    for (int qt = 0; qt < 2; qt++) {
        const int qrow = wrow + qt * 16 + ln;
        const float* Qg = Q + ((size_t)(b * S_ + qrow)) * D_ + h * DH_ + g * 8;
        #pragma unroll
        for (int ds = 0; ds < 2; ds++) {
            union { float4 f4[2]; float f[8]; } qf;
            qf.f4[0] = *(const float4*)(Qg + ds * 32);
            qf.f4[1] = *(const float4*)(Qg + ds * 32 + 4);
            union { short8 v; ushort u[8]; } uh, ul;
            #pragma unroll
            for (int i = 0; i < 8; i++) {
                uh.u[i] = f2b_rn(qf.f[i]);
                ul.u[i] = f2b_rn(qf.f[i] - b2f(uh.u[i]));
            }
            qhi[qt][ds] = uh.v; qlo[qt][ds] = ul.v;
        }
    }

    const f32x4 fzero = {0.f, 0.f, 0.f, 0.f};
    f32x4 ot[4][2];
    #pragma unroll
    for (int dt = 0; dt < 4; dt++)
        #pragma unroll
        for (int qt = 0; qt < 2; qt++)
            ot[dt][qt] = fzero;
    float m_run[2] = {-1e30f, -1e30f};
    float l_run[2] = {0.f, 0.f};

    for (int half = 0; half < 2; half++) {
        const int j0h = j0 + half * 64;
        __syncthreads();   // protect LDS before restage

        {
            const int srow = t >> 2, scol = (t & 3) << 4;
            const float* Kg = K + ((size_t)(b * S_ + j0h + srow)) * D_ + h * DH_ + scol;
            const float* Vg = V + ((size_t)(b * S_ + j0h + srow)) * D_ + h * DH_ + scol;
            union { float4 f4[4]; float f[16]; } kf, vf;
            kf.f4[0] = *(const float4*)(Kg);
            kf.f4[1] = *(const float4*)(Kg + 4);
            kf.f4[2] = *(const float4*)(Kg + 8);
            kf.f4[3] = *(const float4*)(Kg + 12);
            vf.f4[0] = *(const float4*)(Vg);
            vf.f4[1] = *(const float4*)(Vg + 4);
            vf.f4[2] = *(const float4*)(Vg + 8);
            vf.f4[3] = *(const float4*)(Vg + 12);
            union { uint4 d[2]; ushort u[16]; } uh, ul;
            #pragma unroll
            for (int i = 0; i < 16; i++) {
                uh.u[i] = f2b_rn(kf.f[i]);
                ul.u[i] = f2b_rn(kf.f[i] - b2f(uh.u[i]));
            }
            const int c8 = (t & 3) << 1;
            *(uint4*)&sKhi[swzi(srow, c8)]     = uh.d[0];
            *(uint4*)&sKhi[swzi(srow, c8 + 1)] = uh.d[1];
            *(uint4*)&sKlo[swzi(srow, c8)]     = ul.d[0];
            *(uint4*)&sKlo[swzi(srow, c8 + 1)] = ul.d[1];
            #pragma unroll
            for (int i = 0; i < 16; i++) sPool[srow * 65 + scol + i] = vf.f[i];
        }
        __syncthreads();
        {
            const int drow = t >> 2, kcol = (t & 3) << 4;
            union { uint4 d[2]; ushort u[16]; } uh, ul;
            #pragma unroll
            for (int i = 0; i < 16; i++) {
                const float f = sPool[(kcol + i) * 65 + drow];
                uh.u[i] = f2b_rn(f);
                ul.u[i] = f2b_rn(f - b2f(uh.u[i]));
            }
            const int c8 = (t & 3) << 1;
            *(uint4*)&sVthi[swzi(drow, c8)]     = uh.d[0];
            *(uint4*)&sVthi[swzi(drow, c8 + 1)] = uh.d[1];
            *(uint4*)&sVtlo[swzi(drow, c8)]     = ul.d[0];
            *(uint4*)&sVtlo[swzi(drow, c8 + 1)] = ul.d[1];
        }
        __syncthreads();

        if (wrow + 31 < j0h) continue;

        ushort* sPw = (ushort*)sPool + w * 4096;

        f32x4 sT[2][4];
        #pragma unroll
        for (int qt = 0; qt < 2; qt++)
            #pragma unroll
            for (int kt = 0; kt < 4; kt++)
                sT[qt][kt] = fzero;
        #pragma unroll
        for (int ds = 0; ds < 2; ds++) {
            #pragma unroll
            for (int kt = 0; kt < 4; kt++) {
                const int krow = kt * 16 + ln;
                const short8 khi = *(const short8*)&sKhi[swzi(krow, ds * 4 + g)];
                const short8 klo = *(const short8*)&sKlo[swzi(krow, ds * 4 + g)];
                #pragma unroll
                for (int qt = 0; qt < 2; qt++) {
                    sT[qt][kt] = __builtin_amdgcn_mfma_f32_16x16x32_bf16(khi, qhi[qt][ds], sT[qt][kt], 0, 0, 0);
                    sT[qt][kt] = __builtin_amdgcn_mfma_f32_16x16x32_bf16(khi, qlo[qt][ds], sT[qt][kt], 0, 0, 0);
                    sT[qt][kt] = __builtin_amdgcn_mfma_f32_16x16x32_bf16(klo, qhi[qt][ds], sT[qt][kt], 0, 0, 0);
                }
            }
        }

        #pragma unroll
        for (int qt = 0; qt < 2; qt++) {
            const int qg = wrow + qt * 16 + ln;
            float pv[16];
            float mq = -1e30f;
            #pragma unroll
            for (int kt = 0; kt < 4; kt++)
                #pragma unroll
                for (int r = 0; r < 4; r++) {
                    const int kg = j0h + kt * 16 + g * 4 + r;
                    float s = sT[qt][kt][r] * 0.125f;
                    s = (kg <= qg) ? s : -1e30f;
                    pv[kt * 4 + r] = s;
                    mq = fmaxf(mq, s);
                }
            mq = fmaxf(mq, __shfl_xor(mq, 16));
            mq = fmaxf(mq, __shfl_xor(mq, 32));
            const float mN = fmaxf(m_run[qt], mq);
            const float base = (mN < -1e29f) ? 0.f : mN;
            const float a = __expf(m_run[qt] - mN);
            m_run[qt] = mN;
            float lq = 0.f;
            #pragma unroll
            for (int i = 0; i < 16; i++) {
                const float e = __expf(pv[i] - base);
                pv[i] = e;
                lq += e;
            }
            lq += __shfl_xor(lq, 16);
            lq += __shfl_xor(lq, 32);
            l_run[qt] = l_run[qt] * a + lq;
            #pragma unroll
            for (int dt = 0; dt < 4; dt++)
                ot[dt][qt] *= a;

            const int qrow = qt * 16 + ln;
            #pragma unroll
            for (int kt = 0; kt < 4; kt++) {
                union { uint2 d; ushort u[4]; } h4, l4;
                #pragma unroll
                for (int r = 0; r < 4; r++) {
                    const float f = pv[kt * 4 + r];
                    h4.u[r] = f2b_rn(f);
                    l4.u[r] = f2b_rn(f - b2f(h4.u[r]));
                }
                const int c8 = kt * 2 + (g >> 1);
                const int idx = qrow * 64 + ((c8 ^ (qrow & 7)) << 3) + ((g & 1) << 2);
                *(uint2*)&sPw[idx] = h4.d;
                *(uint2*)&sPw[2048 + idx] = l4.d;
            }
        }

        #pragma unroll
        for (int ks = 0; ks < 2; ks++) {
            short8 pfh[2], pfl[2];
            #pragma unroll
            for (int qt = 0; qt < 2; qt++) {
                const int qrow = qt * 16 + ln;
                const int idx = qrow * 64 + (((ks * 4 + g) ^ (qrow & 7)) << 3);
                pfh[qt] = *(const short8*)&sPw[idx];
                pfl[qt] = *(const short8*)&sPw[2048 + idx];
            }
            #pragma unroll
            for (int dt = 0; dt < 4; dt++) {
                const int drow = dt * 16 + ln;
                const short8 vh = *(const short8*)&sVthi[swzi(drow, ks * 4 + g)];
                const short8 vl = *(const short8*)&sVtlo[swzi(drow, ks * 4 + g)];
                #pragma unroll
                for (int qt = 0; qt < 2; qt++) {
                    ot[dt][qt] = __builtin_amdgcn_mfma_f32_16x16x32_bf16(vh, pfh[qt], ot[dt][qt], 0, 0, 0);
                    ot[dt][qt] = __builtin_amdgcn_mfma_f32_16x16x32_bf16(vh, pfl[qt], ot[dt][qt], 0, 0, 0);
                    ot[dt][qt] = __builtin_amdgcn_mfma_f32_16x16x32_bf16(vl, pfh[qt], ot[dt][qt], 0, 0, 0);
                }
            }
        }
    }

    #pragma unroll
    for (int qt = 0; qt < 2; qt++) {
        const int qg = wrow + qt * 16 + ln;
        const int g2 = qg >> 7;                     // == rblk
        const size_t slot = (size_t)bh * NSLOT_BH + 64 * g2 * (g2 + 1)
                          + (size_t)(qg & 127) * (g2 + 1) + sp;
        if (g == 0) { pm[slot] = m_run[qt]; pl[slot] = l_run[qt]; }
        float* od = po + slot * 64 + g * 4;
        #pragma unroll
        for (int dt = 0; dt < 4; dt++)
            *(f32x4*)(od + dt * 16) = ot[dt][qt];
    }
}

// ---------- merge split partials (single-pass online merge) ----------
__global__ __launch_bounds__(256) void attn_combine_kernel(
    const float* __restrict__ pm, const float* __restrict__ pl,
    const float* __restrict__ po, float* __restrict__ AO)
{
    const int gth = blockIdx.x * 256 + threadIdx.x;
    const int r = gth >> 6, d = gth & 63;
    const int i = r & 1023, bh = r >> 10;
    const int b = bh >> 3, h = bh & 7;
    const int g = i >> 7;
    const int ns = g + 1;
    const size_t slot0 = (size_t)bh * NSLOT_BH + 64 * g * (g + 1)
                       + (size_t)(i & 127) * (g + 1);
    float mstar = -INFINITY, lstar = 0.f, ostar = 0.f;
    for (int s = 0; s < ns; s++) {
        const float mi = pm[slot0 + s];
        const float nm = fmaxf(mstar, mi);
        const float a = __expf(mstar - nm);
        const float w = __expf(mi - nm);
        lstar = lstar * a + pl[slot0 + s] * w;
        ostar = ostar * a + po[(slot0 + s) * 64 + d] * w;
        mstar = nm;
    }
    AO[((size_t)(b * S_ + i)) * D_ + h * DH_ + d] = ostar / lstar;
}

// ---------- projection via MFMA (bf16 hi/lo 3-term) + ploss fold -----------
__global__ __launch_bounds__(256) void proj_kernel(
    const float* __restrict__ A,
    const ushort* __restrict__ Wth, const ushort* __restrict__ Wtl,
    const float* __restrict__ acc,
    float* __restrict__ out, float* __restrict__ outp)
{
    if (blockIdx.x == 0 && threadIdx.x == 0) {
        float ssum = 0.f;
        for (int c = 0; c < 8; c++) {
            ssum += acc[c]      / (acc[8 + c]  + 1e-8f);
            ssum += acc[16 + c] / (acc[24 + c] + 1e-8f);
        }
        outp[0] = ssum * 0.125f;
    }
    const int tb = (blockIdx.x >> 4) * 64;   // 32 token tiles
    const int cb = (blockIdx.x & 15) * 32;   // 16 col tiles
    const int t = threadIdx.x, w = t >> 6, lane = t & 63;
    const int ln = lane & 15, ko = (lane >> 4) * 8;
    const int tok = tb + w * 16 + ln;

    const f32x4 fz = {0.f, 0.f, 0.f, 0.f};
    f32x4 acc2[2];
    acc2[0] = fz; acc2[1] = fz;

    const float* Ap = A + (size_t)tok * 512 + ko;
    #pragma unroll 4
    for (int ks = 0; ks < 512; ks += 32) {
        union { float4 f4[2]; float f[8]; } af;
        af.f4[0] = *(const float4*)(Ap + ks);
        af.f4[1] = *(const float4*)(Ap + ks + 4);
        union { short8 v; ushort u[8]; } ah, al;
        #pragma unroll
        for (int i = 0; i < 8; i++) {
            ah.u[i] = f2b_rn(af.f[i]);
            al.u[i] = f2b_rn(af.f[i] - b2f(ah.u[i]));
        }
        #pragma unroll
        for (int ct = 0; ct < 2; ct++) {
            const size_t wb = (size_t)(cb + ct * 16 + ln) * 512 + ks + ko;
            const short8 bh = *(const short8*)(Wth + wb);
            const short8 bl = *(const short8*)(Wtl + wb);
            acc2[ct] = __builtin_amdgcn_mfma_f32_16x16x32_bf16(ah.v, bh, acc2[ct], 0, 0, 0);
            acc2[ct] = __builtin_amdgcn_mfma_f32_16x16x32_bf16(al.v, bh, acc2[ct], 0, 0, 0);
            acc2[ct] = __builtin_amdgcn_mfma_f32_16x16x32_bf16(ah.v, bl, acc2[ct], 0, 0, 0);
        }
    }
    #pragma unroll
    for (int ct = 0; ct < 2; ct++) {
        #pragma unroll
        for (int r = 0; r < 4; r++) {
            const int row = tb + w * 16 + (lane >> 4) * 4 + r;
            out[(size_t)row * 512 + cb + ct * 16 + ln] = acc2[ct][r];
        }
    }
}

extern "C" void kernel_launch(void* const* d_in, const int* in_sizes, int n_in,
                              void* d_out, int out_size, void* d_ws, size_t ws_size,
                              hipStream_t stream) {
    const float* x          = (const float*)d_in[0];
    const float* qk_pos     = (const float*)d_in[1];
    const float* v_pos      = (const float*)d_in[2];
    const float* tauQ       = (const float*)d_in[3];
    const float* tauK       = (const float*)d_in[4];
    const float* tauV       = (const float*)d_in[5];
    const float* qk_neurons = (const float*)d_in[6];
    const float* v_neurons  = (const float*)d_in[7];
    const float* npos_qk    = (const float*)d_in[8];
    const float* npos_v     = (const float*)d_in[9];
    const int*   cm_qk      = (const int*)d_in[10];
    const int*   cm_v       = (const int*)d_in[11];
    const float* pos_min    = (const float*)d_in[12];
    const float* pos_range  = (const float*)d_in[13];
    const float* expand_O   = (const float*)d_in[14];

    float* ws = (float*)d_ws;
    const size_t TDf = (size_t)NTOK * D_;     // 1,048,576 floats
    float* Q   = ws;
    float* K   = ws + TDf;
    float* V   = ws + 2 * TDf;
    float* AO  = ws + 3 * TDf;
    float* acc = ws + 4 * TDf;                // 64 float slots
    int*   order_qk = (int*)(ws + 4 * TDf + 64);
    int*   order_v  = order_qk + NTOK;
    int2*  desc_qk  = (int2*)(order_v + NTOK);
    int2*  desc_v   = desc_qk + NG2;
    const size_t head = 4 * TDf + 64 + 2 * NTOK + 4 * NG2;  // float units

    float* pm = ws + head;                    // NSLOTS
    float* pl = pm + (size_t)NSLOTS;
    float* po = pl + (size_t)NSLOTS;          // NSLOTS*64
    ushort* Wth = (ushort*)(po + (size_t)NSLOTS * 64);   // 512*512 ushort
    ushort* Wtl = Wth + 512 * 512;

    float* out = (float*)d_out;

    sort_wprep_kernel<<<66, 1024, 0, stream>>>(qk_pos, v_pos, pos_min, pos_range,
                                               order_qk, order_v, desc_qk, desc_v,
                                               acc, expand_O, Wth, Wtl);
    qkv_fused<<<2 * NG2, 256, 0, stream>>>(desc_qk, order_qk, desc_v, order_v,
                                           x, qk_pos, v_pos, tauQ, tauK, tauV,
                                           qk_neurons, v_neurons, npos_qk, npos_v,
                                           cm_qk, cm_v, pos_min, pos_range,
                                           Q, K, V, acc);
    attn_partial_kernel<<<16 * 36, 256, 0, stream>>>(Q, K, V, pm, pl, po);
    attn_combine_kernel<<<(NROWS * 64) / 256, 256, 0, stream>>>(pm, pl, po, AO);
    proj_kernel<<<512, 256, 0, stream>>>(AO, Wth, Wtl, acc, out, out + TDf);
}